// Round 3
// baseline (2542.073 us; speedup 1.0000x reference)
//
#include <hip/hip_runtime.h>

#define B_SZ 2
#define L_SZ 2048
#define DMODEL 1024
#define DINNER 2048
#define DSTATE 16
#define DTRANK 64
#define ROWS (B_SZ * L_SZ) /* 4096 */

#define TILE 128
#define BKQ 16

typedef unsigned short bf16;

__device__ __forceinline__ float bf2f(bf16 s) {
  return __uint_as_float(((unsigned)s) << 16);
}
__device__ __forceinline__ bf16 f2bf(float f) {  // round-to-nearest-even
  unsigned u = __float_as_uint(f);
  unsigned r = u + 0x7FFF + ((u >> 16) & 1);
  return (bf16)(r >> 16);
}
__device__ __forceinline__ float softplus_f(float x) {
  return (x > 20.f) ? x : log1pf(__expf(x));
}
__device__ __forceinline__ float silu_f(float x) {
  return x / (1.f + __expf(-x));
}

// --- A-tile loaders: 8 contiguous elements -> float[8] ---
__device__ __forceinline__ void load8(const float* p, float* r) {
  float4 a0 = *(const float4*)p;
  float4 a1 = *(const float4*)(p + 4);
  r[0] = a0.x; r[1] = a0.y; r[2] = a0.z; r[3] = a0.w;
  r[4] = a1.x; r[5] = a1.y; r[6] = a1.z; r[7] = a1.w;
}
__device__ __forceinline__ void load8(const bf16* p, float* r) {
  ushort4 a0 = *(const ushort4*)p;
  ushort4 a1 = *(const ushort4*)(p + 4);
  r[0] = bf2f(a0.x); r[1] = bf2f(a0.y); r[2] = bf2f(a0.z); r[3] = bf2f(a0.w);
  r[4] = bf2f(a1.x); r[5] = bf2f(a1.y); r[6] = bf2f(a1.z); r[7] = bf2f(a1.w);
}

// --- C writers: 4 floats at &C[row*ldc+col] (col % 4 == 0) ---
__device__ __forceinline__ void store4(float* C, size_t off, float4 v) {
  *(float4*)&C[off] = v;
}
__device__ __forceinline__ void store4(bf16* C, size_t off, float4 v) {
  ushort4 w;
  w.x = f2bf(v.x); w.y = f2bf(v.y); w.z = f2bf(v.z); w.w = f2bf(v.w);
  *(ushort4*)&C[off] = w;
}

// C[M x N] = A[M x K](lda) * B[K x N](ldb); M,N multiples of 128, K multiple of 16.
// EPI==1: C = softplus(acc + bias[col]).  Math is fp32; AT/CT control storage.
template <typename AT, typename CT, int EPI>
__global__ __launch_bounds__(256) void gemm128(
    const AT* __restrict__ A, int lda,
    const float* __restrict__ Bm, int ldb,
    CT* __restrict__ C, int ldc,
    int K, const float* __restrict__ bias) {
  __shared__ float As[BKQ][TILE + 4];  // +4: float4-aligned, no bank conflicts
  __shared__ float Bs[BKQ][TILE];
  const int tid = threadIdx.x;
  const int tx = tid & 15, ty = tid >> 4;
  const int bm = blockIdx.y * TILE, bn = blockIdx.x * TILE;
  const int am = tid >> 1, ak = (tid & 1) * 8;   // A staging: 128 rows x 16 k
  const int bk = tid >> 4, bc = (tid & 15) * 8;  // B staging: 16 k x 128 cols

  const AT* Ap = A + (size_t)(bm + am) * lda + ak;
  const float* Bp = Bm + (size_t)bk * ldb + bn + bc;

  float acc[8][8];
#pragma unroll
  for (int i = 0; i < 8; ++i)
#pragma unroll
    for (int j = 0; j < 8; ++j) acc[i][j] = 0.f;

  for (int k0 = 0; k0 < K; k0 += BKQ) {
    float ar8[8];
    load8(Ap, ar8);
    float4 b0 = *(const float4*)(Bp);
    float4 b1 = *(const float4*)(Bp + 4);
    __syncthreads();  // previous compute done before overwriting LDS
#pragma unroll
    for (int j = 0; j < 8; ++j) As[ak + j][am] = ar8[j];
    *(float4*)&Bs[bk][bc] = b0;
    *(float4*)&Bs[bk][bc + 4] = b1;
    __syncthreads();
#pragma unroll
    for (int k = 0; k < BKQ; ++k) {
      float4 av0 = *(const float4*)&As[k][ty * 4];
      float4 av1 = *(const float4*)&As[k][64 + ty * 4];
      float4 bv0 = *(const float4*)&Bs[k][tx * 4];
      float4 bv1 = *(const float4*)&Bs[k][64 + tx * 4];
      float ar[8] = {av0.x, av0.y, av0.z, av0.w, av1.x, av1.y, av1.z, av1.w};
      float br[8] = {bv0.x, bv0.y, bv0.z, bv0.w, bv1.x, bv1.y, bv1.z, bv1.w};
#pragma unroll
      for (int i = 0; i < 8; ++i)
#pragma unroll
        for (int j = 0; j < 8; ++j)
          acc[i][j] = fmaf(ar[i], br[j], acc[i][j]);
    }
    Ap += BKQ;
    Bp += (size_t)BKQ * ldb;
  }

#pragma unroll
  for (int ih = 0; ih < 2; ++ih)
#pragma unroll
    for (int i = 0; i < 4; ++i) {
      const int row = bm + ih * 64 + ty * 4 + i;
#pragma unroll
      for (int jh = 0; jh < 2; ++jh) {
        const int col = bn + jh * 64 + tx * 4;
        float4 v;
        v.x = acc[ih * 4 + i][jh * 4 + 0];
        v.y = acc[ih * 4 + i][jh * 4 + 1];
        v.z = acc[ih * 4 + i][jh * 4 + 2];
        v.w = acc[ih * 4 + i][jh * 4 + 3];
        if (EPI == 1) {
          v.x = softplus_f(v.x + bias[col + 0]);
          v.y = softplus_f(v.y + bias[col + 1]);
          v.z = softplus_f(v.z + bias[col + 2]);
          v.w = softplus_f(v.w + bias[col + 3]);
        }
        store4(C, (size_t)row * ldc + col, v);
      }
    }
}

// u = silu(causal_depthwise_conv(xz[:, :, :DINNER]) + conv_b), layout (B*L, DINNER)
__global__ __launch_bounds__(256) void conv_silu_k(
    const bf16* __restrict__ xz, const float* __restrict__ w,
    const float* __restrict__ bias, bf16* __restrict__ u) {
  const int idx = blockIdx.x * 256 + threadIdx.x;  // over ROWS*DINNER exactly
  const int d = idx & (DINNER - 1);
  const int row = idx >> 11;  // DINNER == 2048
  const int l = row & (L_SZ - 1);
  float s = bias[d];
#pragma unroll
  for (int k = 0; k < 4; ++k) {
    const int t = l - 3 + k;
    if (t >= 0)
      s = fmaf(bf2f(xz[(size_t)(row - 3 + k) * (2 * DINNER) + d]), w[d * 4 + k], s);
  }
  u[idx] = f2bf(silu_f(s));
}

// xdbl[ROWS x 96] = u[ROWS x 2048] @ W_x[2048 x 96]; 8 rows per block.
__global__ __launch_bounds__(256) void xdbl_k(
    const bf16* __restrict__ u, const float* __restrict__ Wx,
    float* __restrict__ xdbl) {
  const int tid = threadIdx.x;
  const int r = tid >> 5, c = tid & 31;
  const int row = blockIdx.x * 8 + r;
  const bf16* ur = u + (size_t)row * DINNER;
  float a0 = 0.f, a1 = 0.f, a2 = 0.f;
#pragma unroll 4
  for (int k = 0; k < DINNER; ++k) {
    const float uv = bf2f(ur[k]);
    const float* w = Wx + (size_t)k * 96;
    a0 = fmaf(uv, w[c], a0);
    a1 = fmaf(uv, w[c + 32], a1);
    a2 = fmaf(uv, w[c + 64], a2);
  }
  float* o = xdbl + (size_t)row * 96;
  o[c] = a0; o[c + 32] = a1; o[c + 64] = a2;
}

// Selective scan; thread = (d-slot, n).
// dt lives in xz cols 0..2047 (bf16), z in xz cols 2048..4095 (bf16).
// gated = y*silu(z) overwrites u in place (safe: group reads u[row,d] before lane0 writes).
__global__ __launch_bounds__(256) void scan_k(
    const bf16* __restrict__ xz /*dt|z*/, bf16* __restrict__ u,
    const float* __restrict__ xdbl, const float* __restrict__ A_log,
    const float* __restrict__ Dp) {
  const int n = threadIdx.x & 15;
  const int dq = threadIdx.x >> 4;
  const int d = blockIdx.x * 16 + dq;
  const int b = blockIdx.y;
  const float a = -__expf(A_log[n]);
  const float Dd = Dp[d];
  float h = 0.f;
  size_t rowU = (size_t)b * L_SZ * DINNER + d;
  size_t rowX = (size_t)b * L_SZ * (2 * DINNER) + d;
  size_t rowS = (size_t)b * L_SZ * 96;
  for (int t = 0; t < L_SZ; ++t) {
    const float dtv = bf2f(xz[rowX]);
    const float uv = bf2f(u[rowU]);
    const float bv = xdbl[rowS + DTRANK + n];
    const float cv = xdbl[rowS + DTRANK + DSTATE + n];
    const float abar = __expf(dtv * a);
    h = fmaf(abar, h, dtv * uv * bv);
    float p = h * cv;
    p += __shfl_xor(p, 1, 16);
    p += __shfl_xor(p, 2, 16);
    p += __shfl_xor(p, 4, 16);
    p += __shfl_xor(p, 8, 16);
    if (n == 0) {
      const float zv = bf2f(xz[rowX + DINNER]);
      const float y = fmaf(Dd, uv, p);
      u[rowU] = f2bf(y * silu_f(zv));
    }
    rowU += DINNER;
    rowX += 2 * DINNER;
    rowS += 96;
  }
}

extern "C" void kernel_launch(void* const* d_in, const int* in_sizes, int n_in,
                              void* d_out, int out_size, void* d_ws, size_t ws_size,
                              hipStream_t stream) {
  const float* x      = (const float*)d_in[0];
  const float* W_in   = (const float*)d_in[1];
  const float* conv_w = (const float*)d_in[2];
  const float* conv_b = (const float*)d_in[3];
  const float* A_log  = (const float*)d_in[4];
  const float* Dp     = (const float*)d_in[5];
  const float* W_x    = (const float*)d_in[6];
  const float* W_dt   = (const float*)d_in[7];
  const float* b_dt   = (const float*)d_in[8];
  const float* W_out  = (const float*)d_in[9];
  float* out = (float*)d_out;

  // workspace layout (total ~51.9 MB; ws overflow was the round-2 failure):
  //   xz_bf : ROWS*4096 bf16 = 32 MB   [u_raw | z]; dt overwrites cols 0..2047 after conv
  //   u_bf  : ROWS*2048 bf16 = 16 MB   silu(conv(u_raw)); gated overwrites in place
  //   xdbl  : ROWS*96  fp32  = 1.5 MB
  bf16* xz_bf = (bf16*)d_ws;
  bf16* u_bf  = xz_bf + (size_t)ROWS * 4096;
  float* xdbl = (float*)(u_bf + (size_t)ROWS * DINNER);

  // 1) xz = x @ W_in  (fp32 math, bf16 store)
  gemm128<float, bf16, 0><<<dim3((2 * DINNER) / TILE, ROWS / TILE), 256, 0, stream>>>(
      x, DMODEL, W_in, 2 * DINNER, xz_bf, 2 * DINNER, DMODEL, nullptr);
  // 2) u = silu(conv(xz[:, :DINNER]) + conv_b)
  conv_silu_k<<<(ROWS * DINNER) / 256, 256, 0, stream>>>(xz_bf, conv_w, conv_b, u_bf);
  // 3) xdbl = u @ W_x  (fp32)
  xdbl_k<<<ROWS / 8, 256, 0, stream>>>(u_bf, W_x, xdbl);
  // 4) dt = softplus(xdbl[:, :64] @ W_dt + b_dt) -> xz cols 0..2047 (u_raw dead)
  gemm128<float, bf16, 1><<<dim3(DINNER / TILE, ROWS / TILE), 256, 0, stream>>>(
      xdbl, 96, W_dt, DINNER, xz_bf, 2 * DINNER, DTRANK, b_dt);
  // 5) selective scan + gating; gated -> u_bf in place
  scan_k<<<dim3(DINNER / 16, B_SZ), 256, 0, stream>>>(xz_bf, u_bf, xdbl, A_log, Dp);
  // 6) out = gated @ W_out
  gemm128<bf16, float, 0><<<dim3(DMODEL / TILE, ROWS / TILE), 256, 0, stream>>>(
      u_bf, DINNER, W_out, DMODEL, out, DMODEL, DINNER, nullptr);
}

// Round 4
// 1475.858 us; speedup vs baseline: 1.7224x; 1.7224x over previous
//
#include <hip/hip_runtime.h>

#define B_SZ 2
#define L_SZ 2048
#define DMODEL 1024
#define DINNER 2048
#define DSTATE 16
#define DTRANK 64
#define ROWS (B_SZ * L_SZ) /* 4096 */

#define TILE 128
#define BKQ 16

typedef unsigned short bf16;

__device__ __forceinline__ float bf2f(bf16 s) {
  return __uint_as_float(((unsigned)s) << 16);
}
__device__ __forceinline__ bf16 f2bf(float f) {  // round-to-nearest-even
  unsigned u = __float_as_uint(f);
  unsigned r = u + 0x7FFF + ((u >> 16) & 1);
  return (bf16)(r >> 16);
}
__device__ __forceinline__ float softplus_f(float x) {
  return (x > 20.f) ? x : log1pf(__expf(x));
}
__device__ __forceinline__ float silu_f(float x) {
  return x / (1.f + __expf(-x));
}

// --- A-tile loaders: 8 contiguous elements -> float[8] ---
__device__ __forceinline__ void load8(const float* p, float* r) {
  float4 a0 = *(const float4*)p;
  float4 a1 = *(const float4*)(p + 4);
  r[0] = a0.x; r[1] = a0.y; r[2] = a0.z; r[3] = a0.w;
  r[4] = a1.x; r[5] = a1.y; r[6] = a1.z; r[7] = a1.w;
}
__device__ __forceinline__ void load8(const bf16* p, float* r) {
  ushort4 a0 = *(const ushort4*)p;
  ushort4 a1 = *(const ushort4*)(p + 4);
  r[0] = bf2f(a0.x); r[1] = bf2f(a0.y); r[2] = bf2f(a0.z); r[3] = bf2f(a0.w);
  r[4] = bf2f(a1.x); r[5] = bf2f(a1.y); r[6] = bf2f(a1.z); r[7] = bf2f(a1.w);
}

// --- C writers: 4 floats at &C[row*ldc+col] (col % 4 == 0) ---
__device__ __forceinline__ void store4(float* C, size_t off, float4 v) {
  *(float4*)&C[off] = v;
}
__device__ __forceinline__ void store4(bf16* C, size_t off, float4 v) {
  ushort4 w;
  w.x = f2bf(v.x); w.y = f2bf(v.y); w.z = f2bf(v.z); w.w = f2bf(v.w);
  *(ushort4*)&C[off] = w;
}

// C[M x N] = A[M x K](lda) * B[K x N](ldb); M,N multiples of 128, K multiple of 16.
// EPI==1: C = softplus(acc + bias[col]).  Math is fp32; AT/CT control storage.
template <typename AT, typename CT, int EPI>
__global__ __launch_bounds__(256) void gemm128(
    const AT* __restrict__ A, int lda,
    const float* __restrict__ Bm, int ldb,
    CT* __restrict__ C, int ldc,
    int K, const float* __restrict__ bias) {
  __shared__ float As[BKQ][TILE + 4];  // +4: float4-aligned, no bank conflicts
  __shared__ float Bs[BKQ][TILE];
  const int tid = threadIdx.x;
  const int tx = tid & 15, ty = tid >> 4;
  const int bm = blockIdx.y * TILE, bn = blockIdx.x * TILE;
  const int am = tid >> 1, ak = (tid & 1) * 8;   // A staging: 128 rows x 16 k
  const int bk = tid >> 4, bc = (tid & 15) * 8;  // B staging: 16 k x 128 cols

  const AT* Ap = A + (size_t)(bm + am) * lda + ak;
  const float* Bp = Bm + (size_t)bk * ldb + bn + bc;

  float acc[8][8];
#pragma unroll
  for (int i = 0; i < 8; ++i)
#pragma unroll
    for (int j = 0; j < 8; ++j) acc[i][j] = 0.f;

  for (int k0 = 0; k0 < K; k0 += BKQ) {
    float ar8[8];
    load8(Ap, ar8);
    float4 b0 = *(const float4*)(Bp);
    float4 b1 = *(const float4*)(Bp + 4);
    __syncthreads();  // previous compute done before overwriting LDS
#pragma unroll
    for (int j = 0; j < 8; ++j) As[ak + j][am] = ar8[j];
    *(float4*)&Bs[bk][bc] = b0;
    *(float4*)&Bs[bk][bc + 4] = b1;
    __syncthreads();
#pragma unroll
    for (int k = 0; k < BKQ; ++k) {
      float4 av0 = *(const float4*)&As[k][ty * 4];
      float4 av1 = *(const float4*)&As[k][64 + ty * 4];
      float4 bv0 = *(const float4*)&Bs[k][tx * 4];
      float4 bv1 = *(const float4*)&Bs[k][64 + tx * 4];
      float ar[8] = {av0.x, av0.y, av0.z, av0.w, av1.x, av1.y, av1.z, av1.w};
      float br[8] = {bv0.x, bv0.y, bv0.z, bv0.w, bv1.x, bv1.y, bv1.z, bv1.w};
#pragma unroll
      for (int i = 0; i < 8; ++i)
#pragma unroll
        for (int j = 0; j < 8; ++j)
          acc[i][j] = fmaf(ar[i], br[j], acc[i][j]);
    }
    Ap += BKQ;
    Bp += (size_t)BKQ * ldb;
  }

#pragma unroll
  for (int ih = 0; ih < 2; ++ih)
#pragma unroll
    for (int i = 0; i < 4; ++i) {
      const int row = bm + ih * 64 + ty * 4 + i;
#pragma unroll
      for (int jh = 0; jh < 2; ++jh) {
        const int col = bn + jh * 64 + tx * 4;
        float4 v;
        v.x = acc[ih * 4 + i][jh * 4 + 0];
        v.y = acc[ih * 4 + i][jh * 4 + 1];
        v.z = acc[ih * 4 + i][jh * 4 + 2];
        v.w = acc[ih * 4 + i][jh * 4 + 3];
        if (EPI == 1) {
          v.x = softplus_f(v.x + bias[col + 0]);
          v.y = softplus_f(v.y + bias[col + 1]);
          v.z = softplus_f(v.z + bias[col + 2]);
          v.w = softplus_f(v.w + bias[col + 3]);
        }
        store4(C, (size_t)row * ldc + col, v);
      }
    }
}

// u = silu(causal_depthwise_conv(xz[:, :, :DINNER]) + conv_b), layout (B*L, DINNER)
__global__ __launch_bounds__(256) void conv_silu_k(
    const bf16* __restrict__ xz, const float* __restrict__ w,
    const float* __restrict__ bias, bf16* __restrict__ u) {
  const int idx = blockIdx.x * 256 + threadIdx.x;  // over ROWS*DINNER exactly
  const int d = idx & (DINNER - 1);
  const int row = idx >> 11;  // DINNER == 2048
  const int l = row & (L_SZ - 1);
  float s = bias[d];
#pragma unroll
  for (int k = 0; k < 4; ++k) {
    const int t = l - 3 + k;
    if (t >= 0)
      s = fmaf(bf2f(xz[(size_t)(row - 3 + k) * (2 * DINNER) + d]), w[d * 4 + k], s);
  }
  u[idx] = f2bf(silu_f(s));
}

// xdbl[ROWS x 96] = u[ROWS x 2048] @ W_x[2048 x 96]; 8 rows per block.
__global__ __launch_bounds__(256) void xdbl_k(
    const bf16* __restrict__ u, const float* __restrict__ Wx,
    float* __restrict__ xdbl) {
  const int tid = threadIdx.x;
  const int r = tid >> 5, c = tid & 31;
  const int row = blockIdx.x * 8 + r;
  const bf16* ur = u + (size_t)row * DINNER;
  float a0 = 0.f, a1 = 0.f, a2 = 0.f;
#pragma unroll 4
  for (int k = 0; k < DINNER; ++k) {
    const float uv = bf2f(ur[k]);
    const float* w = Wx + (size_t)k * 96;
    a0 = fmaf(uv, w[c], a0);
    a1 = fmaf(uv, w[c + 32], a1);
    a2 = fmaf(uv, w[c + 64], a2);
  }
  float* o = xdbl + (size_t)row * 96;
  o[c] = a0; o[c + 32] = a1; o[c + 64] = a2;
}

// ---------------------------------------------------------------------------
// Selective scan, register-double-buffered.
// Group = 16 lanes (n = 0..15) per d-channel; 16 d per block; grid (128, B).
// dt in xz cols 0..2047; z in xz cols 2048..4095; gated = y*silu(z) overwrites
// the z slot (each address is LOADED in the chunk prologue strictly before it
// is STORED in that chunk's compute — same wave, program order ⇒ safe).
// Chunk of CH=16 timesteps prefetched one chunk ahead: load→use distance is
// one full chunk-compute (~800 cy) ≥ L2/L3 latency; loop-carried dep = 1 fmaf.
// ---------------------------------------------------------------------------
#define CH 16
#define NC (L_SZ / CH) /* 128 */

#define LOADC(dt_, u_, bv_, cv_, z_, oXZ_, oU_, oS_)                       \
  _Pragma("unroll") for (int j = 0; j < CH; ++j) {                         \
    dt_[j] = bf2f(xz[(oXZ_) + (size_t)j * (2 * DINNER)]);                  \
    z_[j]  = bf2f(xz[(oXZ_) + (size_t)j * (2 * DINNER) + DINNER]);         \
    u_[j]  = bf2f(u[(oU_) + (size_t)j * DINNER]);                          \
    bv_[j] = xdbl[(oS_) + (size_t)j * 96 + 64];                            \
    cv_[j] = xdbl[(oS_) + (size_t)j * 96 + 80];                            \
  }

#define COMPC(dt_, u_, bv_, cv_, z_, oXZ_)                                 \
  _Pragma("unroll") for (int j = 0; j < CH; ++j) {                         \
    const float abar = __expf(dt_[j] * a);                                 \
    h = fmaf(abar, h, dt_[j] * u_[j] * bv_[j]);                            \
    float p = h * cv_[j];                                                  \
    p += __shfl_xor(p, 1, 16);                                             \
    p += __shfl_xor(p, 2, 16);                                             \
    p += __shfl_xor(p, 4, 16);                                             \
    p += __shfl_xor(p, 8, 16);                                             \
    const float y = fmaf(Dd, u_[j], p);                                    \
    const float g = y * silu_f(z_[j]);                                     \
    if (n == 0)                                                            \
      xz[(oXZ_) + (size_t)j * (2 * DINNER) + DINNER] = f2bf(g);            \
  }

__global__ __launch_bounds__(256, 1) void scan_k(
    bf16* xz /* dt | z->gated */, const bf16* __restrict__ u,
    const float* __restrict__ xdbl, const float* __restrict__ A_log,
    const float* __restrict__ Dp) {
  const int n = threadIdx.x & 15;
  const int dq = threadIdx.x >> 4;
  const int d = blockIdx.x * 16 + dq;
  const int b = blockIdx.y;
  const float a = -__expf(A_log[n]);
  const float Dd = Dp[d];
  float h = 0.f;

  size_t oXZ = (size_t)b * L_SZ * (2 * DINNER) + d;
  size_t oU  = (size_t)b * L_SZ * DINNER + d;
  size_t oS  = (size_t)b * L_SZ * 96 + n;

  float dtA[CH], uA[CH], bvA[CH], cvA[CH], zA[CH];
  float dtB[CH], uB[CH], bvB[CH], cvB[CH], zB[CH];

  LOADC(dtA, uA, bvA, cvA, zA, oXZ, oU, oS);
  for (int c = 0; c < NC; c += 2) {
    const size_t xz1 = oXZ + (size_t)CH * (2 * DINNER);
    const size_t u1  = oU  + (size_t)CH * DINNER;
    const size_t s1  = oS  + (size_t)CH * 96;
    LOADC(dtB, uB, bvB, cvB, zB, xz1, u1, s1);
    COMPC(dtA, uA, bvA, cvA, zA, oXZ);
    if (c + 2 < NC) {
      const size_t xz2 = oXZ + (size_t)(2 * CH) * (2 * DINNER);
      const size_t u2  = oU  + (size_t)(2 * CH) * DINNER;
      const size_t s2  = oS  + (size_t)(2 * CH) * 96;
      LOADC(dtA, uA, bvA, cvA, zA, xz2, u2, s2);
    }
    COMPC(dtB, uB, bvB, cvB, zB, xz1);
    oXZ += (size_t)(2 * CH) * (2 * DINNER);
    oU  += (size_t)(2 * CH) * DINNER;
    oS  += (size_t)(2 * CH) * 96;
  }
}

extern "C" void kernel_launch(void* const* d_in, const int* in_sizes, int n_in,
                              void* d_out, int out_size, void* d_ws, size_t ws_size,
                              hipStream_t stream) {
  const float* x      = (const float*)d_in[0];
  const float* W_in   = (const float*)d_in[1];
  const float* conv_w = (const float*)d_in[2];
  const float* conv_b = (const float*)d_in[3];
  const float* A_log  = (const float*)d_in[4];
  const float* Dp     = (const float*)d_in[5];
  const float* W_x    = (const float*)d_in[6];
  const float* W_dt   = (const float*)d_in[7];
  const float* b_dt   = (const float*)d_in[8];
  const float* W_out  = (const float*)d_in[9];
  float* out = (float*)d_out;

  // workspace layout (total ~49.5 MB, proven to fit):
  //   xz_bf : ROWS*4096 bf16 = 32 MB   [u_raw | z]; dt overwrites cols 0..2047
  //           after conv; gated overwrites cols 2048..4095 during scan
  //   u_bf  : ROWS*2048 bf16 = 16 MB   silu(conv(u_raw)); read-only after conv
  //   xdbl  : ROWS*96  fp32  = 1.5 MB
  bf16* xz_bf = (bf16*)d_ws;
  bf16* u_bf  = xz_bf + (size_t)ROWS * 4096;
  float* xdbl = (float*)(u_bf + (size_t)ROWS * DINNER);

  // 1) xz = x @ W_in  (fp32 math, bf16 store)
  gemm128<float, bf16, 0><<<dim3((2 * DINNER) / TILE, ROWS / TILE), 256, 0, stream>>>(
      x, DMODEL, W_in, 2 * DINNER, xz_bf, 2 * DINNER, DMODEL, nullptr);
  // 2) u = silu(conv(xz[:, :DINNER]) + conv_b)
  conv_silu_k<<<(ROWS * DINNER) / 256, 256, 0, stream>>>(xz_bf, conv_w, conv_b, u_bf);
  // 3) xdbl = u @ W_x  (fp32)
  xdbl_k<<<ROWS / 8, 256, 0, stream>>>(u_bf, W_x, xdbl);
  // 4) dt = softplus(xdbl[:, :64] @ W_dt + b_dt) -> xz cols 0..2047 (u_raw dead)
  gemm128<float, bf16, 1><<<dim3(DINNER / TILE, ROWS / TILE), 256, 0, stream>>>(
      xdbl, 96, W_dt, DINNER, xz_bf, 2 * DINNER, DTRANK, b_dt);
  // 5) selective scan + gating; gated -> xz cols 2048..4095 (over z)
  scan_k<<<dim3(DINNER / 16, B_SZ), 256, 0, stream>>>(xz_bf, u_bf, xdbl, A_log, Dp);
  // 6) out = gated @ W_out  (A = xz cols 2048..4095, lda 4096)
  gemm128<bf16, float, 0><<<dim3(DMODEL / TILE, ROWS / TILE), 256, 0, stream>>>(
      xz_bf + DINNER, 2 * DINNER, W_out, DMODEL, out, DMODEL, DINNER, nullptr);
}

// Round 6
// 1248.544 us; speedup vs baseline: 2.0360x; 1.1821x over previous
//
#include <hip/hip_runtime.h>

#define B_SZ 2
#define L_SZ 2048
#define DMODEL 1024
#define DINNER 2048
#define DSTATE 16
#define DTRANK 64
#define ROWS (B_SZ * L_SZ) /* 4096 */

#define TILE 128
#define BKQ 16

typedef unsigned short bf16;

__device__ __forceinline__ float bf2f(bf16 s) {
  return __uint_as_float(((unsigned)s) << 16);
}
__device__ __forceinline__ bf16 f2bf(float f) {  // round-to-nearest-even
  unsigned u = __float_as_uint(f);
  unsigned r = u + 0x7FFF + ((u >> 16) & 1);
  return (bf16)(r >> 16);
}
__device__ __forceinline__ float softplus_f(float x) {
  return (x > 20.f) ? x : log1pf(__expf(x));
}
__device__ __forceinline__ float silu_f(float x) {
  return x / (1.f + __expf(-x));
}

// --- A-tile loaders: 8 contiguous elements -> float[8] ---
__device__ __forceinline__ void load8(const float* p, float* r) {
  float4 a0 = *(const float4*)p;
  float4 a1 = *(const float4*)(p + 4);
  r[0] = a0.x; r[1] = a0.y; r[2] = a0.z; r[3] = a0.w;
  r[4] = a1.x; r[5] = a1.y; r[6] = a1.z; r[7] = a1.w;
}
__device__ __forceinline__ void load8(const bf16* p, float* r) {
  ushort4 a0 = *(const ushort4*)p;
  ushort4 a1 = *(const ushort4*)(p + 4);
  r[0] = bf2f(a0.x); r[1] = bf2f(a0.y); r[2] = bf2f(a0.z); r[3] = bf2f(a0.w);
  r[4] = bf2f(a1.x); r[5] = bf2f(a1.y); r[6] = bf2f(a1.z); r[7] = bf2f(a1.w);
}

// --- C writers: 4 floats at &C[row*ldc+col] (col % 4 == 0) ---
__device__ __forceinline__ void store4(float* C, size_t off, float4 v) {
  *(float4*)&C[off] = v;
}
__device__ __forceinline__ void store4(bf16* C, size_t off, float4 v) {
  ushort4 w;
  w.x = f2bf(v.x); w.y = f2bf(v.y); w.z = f2bf(v.z); w.w = f2bf(v.w);
  *(ushort4*)&C[off] = w;
}

// C[M x N] = A[M x K](lda) * B[K x N](ldb); M,N multiples of 128, K multiple of 16.
// EPI==1: C = softplus(acc + bias[col]).  Math is fp32; AT/CT control storage.
template <typename AT, typename CT, int EPI>
__global__ __launch_bounds__(256) void gemm128(
    const AT* __restrict__ A, int lda,
    const float* __restrict__ Bm, int ldb,
    CT* __restrict__ C, int ldc,
    int K, const float* __restrict__ bias) {
  __shared__ float As[BKQ][TILE + 4];  // +4: float4-aligned, no bank conflicts
  __shared__ float Bs[BKQ][TILE];
  const int tid = threadIdx.x;
  const int tx = tid & 15, ty = tid >> 4;
  const int bm = blockIdx.y * TILE, bn = blockIdx.x * TILE;
  const int am = tid >> 1, ak = (tid & 1) * 8;   // A staging: 128 rows x 16 k
  const int bk = tid >> 4, bc = (tid & 15) * 8;  // B staging: 16 k x 128 cols

  const AT* Ap = A + (size_t)(bm + am) * lda + ak;
  const float* Bp = Bm + (size_t)bk * ldb + bn + bc;

  float acc[8][8];
#pragma unroll
  for (int i = 0; i < 8; ++i)
#pragma unroll
    for (int j = 0; j < 8; ++j) acc[i][j] = 0.f;

  for (int k0 = 0; k0 < K; k0 += BKQ) {
    float ar8[8];
    load8(Ap, ar8);
    float4 b0 = *(const float4*)(Bp);
    float4 b1 = *(const float4*)(Bp + 4);
    __syncthreads();  // previous compute done before overwriting LDS
#pragma unroll
    for (int j = 0; j < 8; ++j) As[ak + j][am] = ar8[j];
    *(float4*)&Bs[bk][bc] = b0;
    *(float4*)&Bs[bk][bc + 4] = b1;
    __syncthreads();
#pragma unroll
    for (int k = 0; k < BKQ; ++k) {
      float4 av0 = *(const float4*)&As[k][ty * 4];
      float4 av1 = *(const float4*)&As[k][64 + ty * 4];
      float4 bv0 = *(const float4*)&Bs[k][tx * 4];
      float4 bv1 = *(const float4*)&Bs[k][64 + tx * 4];
      float ar[8] = {av0.x, av0.y, av0.z, av0.w, av1.x, av1.y, av1.z, av1.w};
      float br[8] = {bv0.x, bv0.y, bv0.z, bv0.w, bv1.x, bv1.y, bv1.z, bv1.w};
#pragma unroll
      for (int i = 0; i < 8; ++i)
#pragma unroll
        for (int j = 0; j < 8; ++j)
          acc[i][j] = fmaf(ar[i], br[j], acc[i][j]);
    }
    Ap += BKQ;
    Bp += (size_t)BKQ * ldb;
  }

#pragma unroll
  for (int ih = 0; ih < 2; ++ih)
#pragma unroll
    for (int i = 0; i < 4; ++i) {
      const int row = bm + ih * 64 + ty * 4 + i;
#pragma unroll
      for (int jh = 0; jh < 2; ++jh) {
        const int col = bn + jh * 64 + tx * 4;
        float4 v;
        v.x = acc[ih * 4 + i][jh * 4 + 0];
        v.y = acc[ih * 4 + i][jh * 4 + 1];
        v.z = acc[ih * 4 + i][jh * 4 + 2];
        v.w = acc[ih * 4 + i][jh * 4 + 3];
        if (EPI == 1) {
          v.x = softplus_f(v.x + bias[col + 0]);
          v.y = softplus_f(v.y + bias[col + 1]);
          v.z = softplus_f(v.z + bias[col + 2]);
          v.w = softplus_f(v.w + bias[col + 3]);
        }
        store4(C, (size_t)row * ldc + col, v);
      }
    }
}

// u = silu(causal_depthwise_conv(xz[:, :, :DINNER]) + conv_b), layout (B*L, DINNER)
__global__ __launch_bounds__(256) void conv_silu_k(
    const bf16* __restrict__ xz, const float* __restrict__ w,
    const float* __restrict__ bias, bf16* __restrict__ u) {
  const int idx = blockIdx.x * 256 + threadIdx.x;  // over ROWS*DINNER exactly
  const int d = idx & (DINNER - 1);
  const int row = idx >> 11;  // DINNER == 2048
  const int l = row & (L_SZ - 1);
  float s = bias[d];
#pragma unroll
  for (int k = 0; k < 4; ++k) {
    const int t = l - 3 + k;
    if (t >= 0)
      s = fmaf(bf2f(xz[(size_t)(row - 3 + k) * (2 * DINNER) + d]), w[d * 4 + k], s);
  }
  u[idx] = f2bf(silu_f(s));
}

// xdbl[ROWS x 96] = u[ROWS x 2048] @ W_x[2048 x 96]; 8 rows per block.
__global__ __launch_bounds__(256) void xdbl_k(
    const bf16* __restrict__ u, const float* __restrict__ Wx,
    float* __restrict__ xdbl) {
  const int tid = threadIdx.x;
  const int r = tid >> 5, c = tid & 31;
  const int row = blockIdx.x * 8 + r;
  const bf16* ur = u + (size_t)row * DINNER;
  float a0 = 0.f, a1 = 0.f, a2 = 0.f;
#pragma unroll 4
  for (int k = 0; k < DINNER; ++k) {
    const float uv = bf2f(ur[k]);
    const float* w = Wx + (size_t)k * 96;
    a0 = fmaf(uv, w[c], a0);
    a1 = fmaf(uv, w[c + 32], a1);
    a2 = fmaf(uv, w[c + 64], a2);
  }
  float* o = xdbl + (size_t)row * 96;
  o[c] = a0; o[c + 32] = a1; o[c + 64] = a2;
}

// ---------------------------------------------------------------------------
// Segmented selective scan (3 phases). h_t = abar_t*h_{t-1} + x_t is linear, so
// split L into SEGS segments: phase1 scans each segment from h=0 emitting
// (prod abar, h_end); phase2 combines summaries into per-segment start states;
// phase3 re-scans each segment from its true start, with y/silu-gating.
// 16x parallelism vs monolithic scan (round-4 was latency-bound: 630 cy/t,
// occupancy 12%, VGPR=92 proved the 160-reg prefetch got sunk by the compiler).
// CH=8 keeps double-buffer at 80 regs; sched_barrier(0) pins prefetch issue.
// ---------------------------------------------------------------------------
#define SEGS 16
#define SEGL (L_SZ / SEGS) /* 128 */
#define CH 8
#define NCH (SEGL / CH) /* 16 */

#define LOAD1(dt_, u_, bv_, oXZ_, oU_, oS_)                                \
  _Pragma("unroll") for (int j = 0; j < CH; ++j) {                         \
    dt_[j] = bf2f(xz[(oXZ_) + (size_t)j * (2 * DINNER)]);                  \
    u_[j]  = bf2f(u[(oU_) + (size_t)j * DINNER]);                         \
    bv_[j] = xdbl[(oS_) + (size_t)j * 96 + 64];                            \
  }

#define COMP1(dt_, u_, bv_)                                                \
  _Pragma("unroll") for (int j = 0; j < CH; ++j) {                         \
    const float abar = __expf(dt_[j] * a);                                 \
    ap *= abar;                                                            \
    h = fmaf(abar, h, dt_[j] * u_[j] * bv_[j]);                            \
  }

__global__ __launch_bounds__(256, 2) void scan1_k(
    const bf16* __restrict__ xz, const bf16* __restrict__ u,
    const float* __restrict__ xdbl, const float* __restrict__ A_log,
    float* __restrict__ aprod, float* __restrict__ hend) {
  const int n = threadIdx.x & 15;
  const int dq = threadIdx.x >> 4;
  const int d = blockIdx.x * 16 + dq;
  const int b = blockIdx.y >> 4;          // SEGS == 16
  const int s = blockIdx.y & (SEGS - 1);
  const float a = -__expf(A_log[n]);
  const size_t t0 = (size_t)b * L_SZ + (size_t)s * SEGL;
  size_t oXZ = t0 * (2 * DINNER) + d;
  size_t oU  = t0 * DINNER + d;
  size_t oS  = t0 * 96 + n;
  float h = 0.f, ap = 1.f;
  float dtA[CH], uA[CH], bvA[CH];
  float dtB[CH], uB[CH], bvB[CH];
  LOAD1(dtA, uA, bvA, oXZ, oU, oS);
  __builtin_amdgcn_sched_barrier(0);
  for (int c = 0; c < NCH; c += 2) {
    LOAD1(dtB, uB, bvB, oXZ + (size_t)CH * (2 * DINNER),
          oU + (size_t)CH * DINNER, oS + (size_t)CH * 96);
    __builtin_amdgcn_sched_barrier(0);
    COMP1(dtA, uA, bvA);
    if (c + 2 < NCH) {
      LOAD1(dtA, uA, bvA, oXZ + (size_t)(2 * CH) * (2 * DINNER),
            oU + (size_t)(2 * CH) * DINNER, oS + (size_t)(2 * CH) * 96);
      __builtin_amdgcn_sched_barrier(0);
    }
    COMP1(dtB, uB, bvB);
    oXZ += (size_t)(2 * CH) * (2 * DINNER);
    oU  += (size_t)(2 * CH) * DINNER;
    oS  += (size_t)(2 * CH) * 96;
  }
  const size_t idx = (((size_t)b * SEGS + s) * DINNER + d) * DSTATE + n;
  aprod[idx] = ap;
  hend[idx]  = h;
}

// phase2: hse[b][s][d][n]: in  = h_end(local) per segment, out = h_start per
// segment. All loads hoisted before stores (per-thread addresses disjoint).
__global__ __launch_bounds__(256) void scan2_k(
    const float* __restrict__ aprod, float* hse) {
  const int n = threadIdx.x & 15;
  const int dq = threadIdx.x >> 4;
  const int d = blockIdx.x * 16 + dq;
  const int b = blockIdx.y;
  const size_t base = ((size_t)b * SEGS * DINNER + d) * DSTATE + n;
  float av[SEGS], ev[SEGS];
#pragma unroll
  for (int s = 0; s < SEGS; ++s) {
    av[s] = aprod[base + (size_t)s * DINNER * DSTATE];
    ev[s] = hse[base + (size_t)s * DINNER * DSTATE];
  }
  float h = 0.f;
#pragma unroll
  for (int s = 0; s < SEGS; ++s) {
    hse[base + (size_t)s * DINNER * DSTATE] = h;
    h = fmaf(av[s], h, ev[s]);
  }
}

#define LOAD3(dt_, u_, bv_, cv_, z_, oXZ_, oU_, oS_)                       \
  _Pragma("unroll") for (int j = 0; j < CH; ++j) {                         \
    dt_[j] = bf2f(xz[(oXZ_) + (size_t)j * (2 * DINNER)]);                  \
    z_[j]  = bf2f(xz[(oXZ_) + (size_t)j * (2 * DINNER) + DINNER]);         \
    u_[j]  = bf2f(u[(oU_) + (size_t)j * DINNER]);                         \
    bv_[j] = xdbl[(oS_) + (size_t)j * 96 + 64];                            \
    cv_[j] = xdbl[(oS_) + (size_t)j * 96 + 80];                            \
  }

#define COMP3(dt_, u_, bv_, cv_, z_, oXZ_)                                 \
  _Pragma("unroll") for (int j = 0; j < CH; ++j) {                         \
    const float abar = __expf(dt_[j] * a);                                 \
    h = fmaf(abar, h, dt_[j] * u_[j] * bv_[j]);                            \
    float p = h * cv_[j];                                                  \
    p += __shfl_xor(p, 1, 16);                                             \
    p += __shfl_xor(p, 2, 16);                                             \
    p += __shfl_xor(p, 4, 16);                                             \
    p += __shfl_xor(p, 8, 16);                                             \
    const float y = fmaf(Dd, u_[j], p);                                    \
    const float g = y * silu_f(z_[j]);                                     \
    if (n == 0)                                                            \
      xz[(oXZ_) + (size_t)j * (2 * DINNER) + DINNER] = f2bf(g);            \
  }

__global__ __launch_bounds__(256, 2) void scan3_k(
    bf16* xz /* dt | z->gated */, const bf16* __restrict__ u,
    const float* __restrict__ xdbl, const float* __restrict__ A_log,
    const float* __restrict__ Dp, const float* __restrict__ hstart) {
  const int n = threadIdx.x & 15;
  const int dq = threadIdx.x >> 4;
  const int d = blockIdx.x * 16 + dq;
  const int b = blockIdx.y >> 4;
  const int s = blockIdx.y & (SEGS - 1);
  const float a = -__expf(A_log[n]);
  const float Dd = Dp[d];
  float h = hstart[(((size_t)b * SEGS + s) * DINNER + d) * DSTATE + n];

  const size_t t0 = (size_t)b * L_SZ + (size_t)s * SEGL;
  size_t oXZ = t0 * (2 * DINNER) + d;
  size_t oU  = t0 * DINNER + d;
  size_t oS  = t0 * 96 + n;

  float dtA[CH], uA[CH], bvA[CH], cvA[CH], zA[CH];
  float dtB[CH], uB[CH], bvB[CH], cvB[CH], zB[CH];

  LOAD3(dtA, uA, bvA, cvA, zA, oXZ, oU, oS);
  __builtin_amdgcn_sched_barrier(0);
  for (int c = 0; c < NCH; c += 2) {
    const size_t xz1 = oXZ + (size_t)CH * (2 * DINNER);
    const size_t u1  = oU  + (size_t)CH * DINNER;
    const size_t s1  = oS  + (size_t)CH * 96;
    LOAD3(dtB, uB, bvB, cvB, zB, xz1, u1, s1);
    __builtin_amdgcn_sched_barrier(0);
    COMP3(dtA, uA, bvA, cvA, zA, oXZ);
    if (c + 2 < NCH) {
      LOAD3(dtA, uA, bvA, cvA, zA, oXZ + (size_t)(2 * CH) * (2 * DINNER),
            oU + (size_t)(2 * CH) * DINNER, oS + (size_t)(2 * CH) * 96);
      __builtin_amdgcn_sched_barrier(0);
    }
    COMP3(dtB, uB, bvB, cvB, zB, xz1);
    oXZ += (size_t)(2 * CH) * (2 * DINNER);
    oU  += (size_t)(2 * CH) * DINNER;
    oS  += (size_t)(2 * CH) * 96;
  }
}

extern "C" void kernel_launch(void* const* d_in, const int* in_sizes, int n_in,
                              void* d_out, int out_size, void* d_ws, size_t ws_size,
                              hipStream_t stream) {
  const float* x      = (const float*)d_in[0];
  const float* W_in   = (const float*)d_in[1];
  const float* conv_w = (const float*)d_in[2];
  const float* conv_b = (const float*)d_in[3];
  const float* A_log  = (const float*)d_in[4];
  const float* Dp     = (const float*)d_in[5];
  const float* W_x    = (const float*)d_in[6];
  const float* W_dt   = (const float*)d_in[7];
  const float* b_dt   = (const float*)d_in[8];
  const float* W_out  = (const float*)d_in[9];
  float* out = (float*)d_out;

  // workspace layout (total ~57.5 MB; 49.5 proven, 168 failed):
  //   xz_bf : ROWS*4096 bf16 = 32 MB  [u_raw|z]; dt over cols 0..2047; gated over z
  //   u_bf  : ROWS*2048 bf16 = 16 MB
  //   xdbl  : ROWS*96  fp32  = 1.5 MB
  //   aprod : B*SEGS*DINNER*DSTATE fp32 = 4 MB
  //   hse   : same, 4 MB (h_end -> h_start in place)
  bf16* xz_bf = (bf16*)d_ws;
  bf16* u_bf  = xz_bf + (size_t)ROWS * 4096;
  float* xdbl = (float*)(u_bf + (size_t)ROWS * DINNER);
  float* aprod = xdbl + (size_t)ROWS * 96;
  float* hse   = aprod + (size_t)B_SZ * SEGS * DINNER * DSTATE;

  // 1) xz = x @ W_in  (fp32 math, bf16 store)
  gemm128<float, bf16, 0><<<dim3((2 * DINNER) / TILE, ROWS / TILE), 256, 0, stream>>>(
      x, DMODEL, W_in, 2 * DINNER, xz_bf, 2 * DINNER, DMODEL, nullptr);
  // 2) u = silu(conv(xz[:, :DINNER]) + conv_b)
  conv_silu_k<<<(ROWS * DINNER) / 256, 256, 0, stream>>>(xz_bf, conv_w, conv_b, u_bf);
  // 3) xdbl = u @ W_x  (fp32)
  xdbl_k<<<ROWS / 8, 256, 0, stream>>>(u_bf, W_x, xdbl);
  // 4) dt = softplus(xdbl[:, :64] @ W_dt + b_dt) -> xz cols 0..2047 (u_raw dead)
  gemm128<float, bf16, 1><<<dim3(DINNER / TILE, ROWS / TILE), 256, 0, stream>>>(
      xdbl, 96, W_dt, DINNER, xz_bf, 2 * DINNER, DTRANK, b_dt);
  // 5) segmented selective scan + gating; gated -> xz cols 2048..4095
  scan1_k<<<dim3(DINNER / 16, B_SZ * SEGS), 256, 0, stream>>>(
      xz_bf, u_bf, xdbl, A_log, aprod, hse);
  scan2_k<<<dim3(DINNER / 16, B_SZ), 256, 0, stream>>>(aprod, hse);
  scan3_k<<<dim3(DINNER / 16, B_SZ * SEGS), 256, 0, stream>>>(
      xz_bf, u_bf, xdbl, A_log, Dp, hse);
  // 6) out = gated @ W_out  (A = xz cols 2048..4095, lda 4096)
  gemm128<bf16, float, 0><<<dim3(DMODEL / TILE, ROWS / TILE), 256, 0, stream>>>(
      xz_bf + DINNER, 2 * DINNER, W_out, DMODEL, out, DMODEL, DINNER, nullptr);
}

// Round 7
// 699.677 us; speedup vs baseline: 3.6332x; 1.7845x over previous
//
#include <hip/hip_runtime.h>

#define B_SZ 2
#define L_SZ 2048
#define DMODEL 1024
#define DINNER 2048
#define DSTATE 16
#define DTRANK 64
#define ROWS (B_SZ * L_SZ) /* 4096 */

#define TILE 128
#define BKQ 16

typedef unsigned short bf16;
typedef unsigned short u16x8 __attribute__((ext_vector_type(8)));
typedef short s16x8 __attribute__((ext_vector_type(8)));
typedef float f32x4 __attribute__((ext_vector_type(4)));

__device__ __forceinline__ float bf2f(bf16 s) {
  return __uint_as_float(((unsigned)s) << 16);
}
__device__ __forceinline__ bf16 f2bf(float f) {  // round-to-nearest-even
  unsigned u = __float_as_uint(f);
  unsigned r = u + 0x7FFF + ((u >> 16) & 1);
  return (bf16)(r >> 16);
}
__device__ __forceinline__ float softplus_f(float x) {
  return (x > 20.f) ? x : log1pf(__expf(x));
}
__device__ __forceinline__ float silu_f(float x) {
  return x / (1.f + __expf(-x));
}

// --- A-tile loaders: 8 contiguous elements -> float[8] ---
__device__ __forceinline__ void load8(const float* p, float* r) {
  float4 a0 = *(const float4*)p;
  float4 a1 = *(const float4*)(p + 4);
  r[0] = a0.x; r[1] = a0.y; r[2] = a0.z; r[3] = a0.w;
  r[4] = a1.x; r[5] = a1.y; r[6] = a1.z; r[7] = a1.w;
}

// --- C writers ---
__device__ __forceinline__ void store4(float* C, size_t off, float4 v) {
  *(float4*)&C[off] = v;
}
__device__ __forceinline__ void store4(bf16* C, size_t off, float4 v) {
  ushort4 w;
  w.x = f2bf(v.x); w.y = f2bf(v.y); w.z = f2bf(v.z); w.w = f2bf(v.w);
  *(ushort4*)&C[off] = w;
}
__device__ __forceinline__ void storeC(float* C, size_t off, float v) { C[off] = v; }
__device__ __forceinline__ void storeC(bf16* C, size_t off, float v) { C[off] = f2bf(v); }

// ---------------------------------------------------------------------------
// bf16 MFMA GEMM: C[M x N] = A[M x K] * BT[N x K]^T, fp32 accumulate.
// 128x128 tile, 4 waves of 64x64 (4x4 fragments of 16x16x32).
// LDS row stride 40 bf16 (=80B): 16B-aligned ds_read_b128, <=4-way bank alias.
// Fragment mapping (m89/m91-verified): A/B lane l: row|col = l&15,
// k = (l>>4)*8+j (8 contiguous bf16); C/D: col = l&15, row = (l>>4)*4+reg.
// ---------------------------------------------------------------------------
#define LSTR 40
template <typename CT>
__global__ __launch_bounds__(256) void gemm_mfma(
    const bf16* __restrict__ A, int lda,
    const bf16* __restrict__ BT, int ldbt,
    CT* __restrict__ C, int ldc, int K) {
  __shared__ alignas(16) bf16 As[128 * LSTR];
  __shared__ alignas(16) bf16 Bs[128 * LSTR];
  const int tid = threadIdx.x;
  const int lane = tid & 63;
  const int wave = tid >> 6;
  const int wm = wave >> 1, wn = wave & 1;
  const int bm = blockIdx.y * 128, bn = blockIdx.x * 128;

  // staging: thread t covers rows (t>>2) and (t>>2)+64, 8 bf16 at quarter t&3
  const int sr = tid >> 2;
  const int sq = tid & 3;
  const bf16* Ap0 = A + (size_t)(bm + sr) * lda + sq * 8;
  const bf16* Ap1 = A + (size_t)(bm + sr + 64) * lda + sq * 8;
  const bf16* Bp0 = BT + (size_t)(bn + sr) * ldbt + sq * 8;
  const bf16* Bp1 = BT + (size_t)(bn + sr + 64) * ldbt + sq * 8;
  bf16* wA0 = &As[sr * LSTR + sq * 8];
  bf16* wA1 = &As[(sr + 64) * LSTR + sq * 8];
  bf16* wB0 = &Bs[sr * LSTR + sq * 8];
  bf16* wB1 = &Bs[(sr + 64) * LSTR + sq * 8];

  const int fr = lane & 15;
  const int fq = lane >> 4;
  const bf16* rA = &As[(wm * 64 + fr) * LSTR + fq * 8];
  const bf16* rB = &Bs[(wn * 64 + fr) * LSTR + fq * 8];

  f32x4 acc[4][4];
#pragma unroll
  for (int i = 0; i < 4; ++i)
#pragma unroll
    for (int j = 0; j < 4; ++j) acc[i][j] = (f32x4){0.f, 0.f, 0.f, 0.f};

  for (int k0 = 0; k0 < K; k0 += 32) {
    u16x8 a0 = *(const u16x8*)Ap0;
    u16x8 a1 = *(const u16x8*)Ap1;
    u16x8 b0 = *(const u16x8*)Bp0;
    u16x8 b1 = *(const u16x8*)Bp1;
    __syncthreads();  // previous compute done before overwriting LDS
    *(u16x8*)wA0 = a0;
    *(u16x8*)wA1 = a1;
    *(u16x8*)wB0 = b0;
    *(u16x8*)wB1 = b1;
    __syncthreads();
    s16x8 af[4], bfr[4];
#pragma unroll
    for (int mi = 0; mi < 4; ++mi) af[mi] = *(const s16x8*)(rA + mi * 16 * LSTR);
#pragma unroll
    for (int ni = 0; ni < 4; ++ni) bfr[ni] = *(const s16x8*)(rB + ni * 16 * LSTR);
#pragma unroll
    for (int mi = 0; mi < 4; ++mi)
#pragma unroll
      for (int ni = 0; ni < 4; ++ni)
        acc[mi][ni] = __builtin_amdgcn_mfma_f32_16x16x32_bf16(
            af[mi], bfr[ni], acc[mi][ni], 0, 0, 0);
    Ap0 += 32; Ap1 += 32; Bp0 += 32; Bp1 += 32;
  }

#pragma unroll
  for (int mi = 0; mi < 4; ++mi)
#pragma unroll
    for (int ni = 0; ni < 4; ++ni) {
      const int col = bn + wn * 64 + ni * 16 + fr;
#pragma unroll
      for (int j = 0; j < 4; ++j) {
        const int row = bm + wm * 64 + mi * 16 + fq * 4 + j;
        storeC(C, (size_t)row * ldc + col, acc[mi][ni][j]);
      }
    }
}

// fp32 -> bf16 elementwise (8/thread)
__global__ __launch_bounds__(256) void cvt_f2b_k(
    const float* __restrict__ src, bf16* __restrict__ dst) {
  const size_t i = ((size_t)blockIdx.x * 256 + threadIdx.x) * 8;
  float4 v0 = *(const float4*)(src + i);
  float4 v1 = *(const float4*)(src + i + 4);
  u16x8 o;
  o[0] = f2bf(v0.x); o[1] = f2bf(v0.y); o[2] = f2bf(v0.z); o[3] = f2bf(v0.w);
  o[4] = f2bf(v1.x); o[5] = f2bf(v1.y); o[6] = f2bf(v1.z); o[7] = f2bf(v1.w);
  *(u16x8*)(dst + i) = o;
}

// dst[C][R] (bf16) = transpose(src[R][C] fp32); 32x32 LDS tiles
__global__ __launch_bounds__(256) void transpose_f2b_k(
    const float* __restrict__ src, bf16* __restrict__ dst, int R, int C) {
  __shared__ float t[32][33];
  const int c0 = blockIdx.x * 32, r0 = blockIdx.y * 32;
  const int tx = threadIdx.x, ty = threadIdx.y;
#pragma unroll
  for (int i = 0; i < 4; ++i)
    t[ty + i * 8][tx] = src[(size_t)(r0 + ty + i * 8) * C + c0 + tx];
  __syncthreads();
#pragma unroll
  for (int i = 0; i < 4; ++i)
    dst[(size_t)(c0 + ty + i * 8) * R + r0 + tx] = f2bf(t[tx][ty + i * 8]);
}

// fp32 tiled GEMM (kept for the small dt GEMM, K=64).
// EPI==1: C = softplus(acc + bias[col]).
template <typename AT, typename CT, int EPI>
__global__ __launch_bounds__(256) void gemm128(
    const AT* __restrict__ A, int lda,
    const float* __restrict__ Bm, int ldb,
    CT* __restrict__ C, int ldc,
    int K, const float* __restrict__ bias) {
  __shared__ float As[BKQ][TILE + 4];
  __shared__ float Bs[BKQ][TILE];
  const int tid = threadIdx.x;
  const int tx = tid & 15, ty = tid >> 4;
  const int bm = blockIdx.y * TILE, bn = blockIdx.x * TILE;
  const int am = tid >> 1, ak = (tid & 1) * 8;
  const int bk = tid >> 4, bc = (tid & 15) * 8;

  const AT* Ap = A + (size_t)(bm + am) * lda + ak;
  const float* Bp = Bm + (size_t)bk * ldb + bn + bc;

  float acc[8][8];
#pragma unroll
  for (int i = 0; i < 8; ++i)
#pragma unroll
    for (int j = 0; j < 8; ++j) acc[i][j] = 0.f;

  for (int k0 = 0; k0 < K; k0 += BKQ) {
    float ar8[8];
    load8(Ap, ar8);
    float4 b0 = *(const float4*)(Bp);
    float4 b1 = *(const float4*)(Bp + 4);
    __syncthreads();
#pragma unroll
    for (int j = 0; j < 8; ++j) As[ak + j][am] = ar8[j];
    *(float4*)&Bs[bk][bc] = b0;
    *(float4*)&Bs[bk][bc + 4] = b1;
    __syncthreads();
#pragma unroll
    for (int k = 0; k < BKQ; ++k) {
      float4 av0 = *(const float4*)&As[k][ty * 4];
      float4 av1 = *(const float4*)&As[k][64 + ty * 4];
      float4 bv0 = *(const float4*)&Bs[k][tx * 4];
      float4 bv1 = *(const float4*)&Bs[k][64 + tx * 4];
      float ar[8] = {av0.x, av0.y, av0.z, av0.w, av1.x, av1.y, av1.z, av1.w};
      float br[8] = {bv0.x, bv0.y, bv0.z, bv0.w, bv1.x, bv1.y, bv1.z, bv1.w};
#pragma unroll
      for (int i = 0; i < 8; ++i)
#pragma unroll
        for (int j = 0; j < 8; ++j)
          acc[i][j] = fmaf(ar[i], br[j], acc[i][j]);
    }
    Ap += BKQ;
    Bp += (size_t)BKQ * ldb;
  }

#pragma unroll
  for (int ih = 0; ih < 2; ++ih)
#pragma unroll
    for (int i = 0; i < 4; ++i) {
      const int row = bm + ih * 64 + ty * 4 + i;
#pragma unroll
      for (int jh = 0; jh < 2; ++jh) {
        const int col = bn + jh * 64 + tx * 4;
        float4 v;
        v.x = acc[ih * 4 + i][jh * 4 + 0];
        v.y = acc[ih * 4 + i][jh * 4 + 1];
        v.z = acc[ih * 4 + i][jh * 4 + 2];
        v.w = acc[ih * 4 + i][jh * 4 + 3];
        if (EPI == 1) {
          v.x = softplus_f(v.x + bias[col + 0]);
          v.y = softplus_f(v.y + bias[col + 1]);
          v.z = softplus_f(v.z + bias[col + 2]);
          v.w = softplus_f(v.w + bias[col + 3]);
        }
        store4(C, (size_t)row * ldc + col, v);
      }
    }
}

// u = silu(causal_depthwise_conv(xz[:, :, :DINNER]) + conv_b), layout (B*L, DINNER)
__global__ __launch_bounds__(256) void conv_silu_k(
    const bf16* __restrict__ xz, const float* __restrict__ w,
    const float* __restrict__ bias, bf16* __restrict__ u) {
  const int idx = blockIdx.x * 256 + threadIdx.x;
  const int d = idx & (DINNER - 1);
  const int row = idx >> 11;
  const int l = row & (L_SZ - 1);
  float s = bias[d];
#pragma unroll
  for (int k = 0; k < 4; ++k) {
    const int t = l - 3 + k;
    if (t >= 0)
      s = fmaf(bf2f(xz[(size_t)(row - 3 + k) * (2 * DINNER) + d]), w[d * 4 + k], s);
  }
  u[idx] = f2bf(silu_f(s));
}

// xdbl[ROWS x 96] = u[ROWS x 2048] @ W_x[2048 x 96]; 8 rows per block.
__global__ __launch_bounds__(256) void xdbl_k(
    const bf16* __restrict__ u, const float* __restrict__ Wx,
    float* __restrict__ xdbl) {
  const int tid = threadIdx.x;
  const int r = tid >> 5, c = tid & 31;
  const int row = blockIdx.x * 8 + r;
  const bf16* ur = u + (size_t)row * DINNER;
  float a0 = 0.f, a1 = 0.f, a2 = 0.f;
#pragma unroll 4
  for (int k = 0; k < DINNER; ++k) {
    const float uv = bf2f(ur[k]);
    const float* w = Wx + (size_t)k * 96;
    a0 = fmaf(uv, w[c], a0);
    a1 = fmaf(uv, w[c + 32], a1);
    a2 = fmaf(uv, w[c + 64], a2);
  }
  float* o = xdbl + (size_t)row * 96;
  o[c] = a0; o[c + 32] = a1; o[c + 64] = a2;
}

// ---------------------------------------------------------------------------
// Segmented selective scan (3 phases) — unchanged from round 6 (validated).
// ---------------------------------------------------------------------------
#define SEGS 16
#define SEGL (L_SZ / SEGS) /* 128 */
#define CH 8
#define NCH (SEGL / CH) /* 16 */

#define LOAD1(dt_, u_, bv_, oXZ_, oU_, oS_)                                \
  _Pragma("unroll") for (int j = 0; j < CH; ++j) {                         \
    dt_[j] = bf2f(xz[(oXZ_) + (size_t)j * (2 * DINNER)]);                  \
    u_[j]  = bf2f(u[(oU_) + (size_t)j * DINNER]);                         \
    bv_[j] = xdbl[(oS_) + (size_t)j * 96 + 64];                            \
  }

#define COMP1(dt_, u_, bv_)                                                \
  _Pragma("unroll") for (int j = 0; j < CH; ++j) {                         \
    const float abar = __expf(dt_[j] * a);                                 \
    ap *= abar;                                                            \
    h = fmaf(abar, h, dt_[j] * u_[j] * bv_[j]);                            \
  }

__global__ __launch_bounds__(256, 2) void scan1_k(
    const bf16* __restrict__ xz, const bf16* __restrict__ u,
    const float* __restrict__ xdbl, const float* __restrict__ A_log,
    float* __restrict__ aprod, float* __restrict__ hend) {
  const int n = threadIdx.x & 15;
  const int dq = threadIdx.x >> 4;
  const int d = blockIdx.x * 16 + dq;
  const int b = blockIdx.y >> 4;
  const int s = blockIdx.y & (SEGS - 1);
  const float a = -__expf(A_log[n]);
  const size_t t0 = (size_t)b * L_SZ + (size_t)s * SEGL;
  size_t oXZ = t0 * (2 * DINNER) + d;
  size_t oU  = t0 * DINNER + d;
  size_t oS  = t0 * 96 + n;
  float h = 0.f, ap = 1.f;
  float dtA[CH], uA[CH], bvA[CH];
  float dtB[CH], uB[CH], bvB[CH];
  LOAD1(dtA, uA, bvA, oXZ, oU, oS);
  __builtin_amdgcn_sched_barrier(0);
  for (int c = 0; c < NCH; c += 2) {
    LOAD1(dtB, uB, bvB, oXZ + (size_t)CH * (2 * DINNER),
          oU + (size_t)CH * DINNER, oS + (size_t)CH * 96);
    __builtin_amdgcn_sched_barrier(0);
    COMP1(dtA, uA, bvA);
    if (c + 2 < NCH) {
      LOAD1(dtA, uA, bvA, oXZ + (size_t)(2 * CH) * (2 * DINNER),
            oU + (size_t)(2 * CH) * DINNER, oS + (size_t)(2 * CH) * 96);
      __builtin_amdgcn_sched_barrier(0);
    }
    COMP1(dtB, uB, bvB);
    oXZ += (size_t)(2 * CH) * (2 * DINNER);
    oU  += (size_t)(2 * CH) * DINNER;
    oS  += (size_t)(2 * CH) * 96;
  }
  const size_t idx = (((size_t)b * SEGS + s) * DINNER + d) * DSTATE + n;
  aprod[idx] = ap;
  hend[idx]  = h;
}

__global__ __launch_bounds__(256) void scan2_k(
    const float* __restrict__ aprod, float* hse) {
  const int n = threadIdx.x & 15;
  const int dq = threadIdx.x >> 4;
  const int d = blockIdx.x * 16 + dq;
  const int b = blockIdx.y;
  const size_t base = ((size_t)b * SEGS * DINNER + d) * DSTATE + n;
  float av[SEGS], ev[SEGS];
#pragma unroll
  for (int s = 0; s < SEGS; ++s) {
    av[s] = aprod[base + (size_t)s * DINNER * DSTATE];
    ev[s] = hse[base + (size_t)s * DINNER * DSTATE];
  }
  float h = 0.f;
#pragma unroll
  for (int s = 0; s < SEGS; ++s) {
    hse[base + (size_t)s * DINNER * DSTATE] = h;
    h = fmaf(av[s], h, ev[s]);
  }
}

#define LOAD3(dt_, u_, bv_, cv_, z_, oXZ_, oU_, oS_)                       \
  _Pragma("unroll") for (int j = 0; j < CH; ++j) {                         \
    dt_[j] = bf2f(xz[(oXZ_) + (size_t)j * (2 * DINNER)]);                  \
    z_[j]  = bf2f(xz[(oXZ_) + (size_t)j * (2 * DINNER) + DINNER]);         \
    u_[j]  = bf2f(u[(oU_) + (size_t)j * DINNER]);                         \
    bv_[j] = xdbl[(oS_) + (size_t)j * 96 + 64];                            \
    cv_[j] = xdbl[(oS_) + (size_t)j * 96 + 80];                            \
  }

#define COMP3(dt_, u_, bv_, cv_, z_, oXZ_)                                 \
  _Pragma("unroll") for (int j = 0; j < CH; ++j) {                         \
    const float abar = __expf(dt_[j] * a);                                 \
    h = fmaf(abar, h, dt_[j] * u_[j] * bv_[j]);                            \
    float p = h * cv_[j];                                                  \
    p += __shfl_xor(p, 1, 16);                                             \
    p += __shfl_xor(p, 2, 16);                                             \
    p += __shfl_xor(p, 4, 16);                                             \
    p += __shfl_xor(p, 8, 16);                                             \
    const float y = fmaf(Dd, u_[j], p);                                    \
    const float g = y * silu_f(z_[j]);                                     \
    if (n == 0)                                                            \
      xz[(oXZ_) + (size_t)j * (2 * DINNER) + DINNER] = f2bf(g);            \
  }

__global__ __launch_bounds__(256, 2) void scan3_k(
    bf16* xz /* dt | z->gated */, const bf16* __restrict__ u,
    const float* __restrict__ xdbl, const float* __restrict__ A_log,
    const float* __restrict__ Dp, const float* __restrict__ hstart) {
  const int n = threadIdx.x & 15;
  const int dq = threadIdx.x >> 4;
  const int d = blockIdx.x * 16 + dq;
  const int b = blockIdx.y >> 4;
  const int s = blockIdx.y & (SEGS - 1);
  const float a = -__expf(A_log[n]);
  const float Dd = Dp[d];
  float h = hstart[(((size_t)b * SEGS + s) * DINNER + d) * DSTATE + n];

  const size_t t0 = (size_t)b * L_SZ + (size_t)s * SEGL;
  size_t oXZ = t0 * (2 * DINNER) + d;
  size_t oU  = t0 * DINNER + d;
  size_t oS  = t0 * 96 + n;

  float dtA[CH], uA[CH], bvA[CH], cvA[CH], zA[CH];
  float dtB[CH], uB[CH], bvB[CH], cvB[CH], zB[CH];

  LOAD3(dtA, uA, bvA, cvA, zA, oXZ, oU, oS);
  __builtin_amdgcn_sched_barrier(0);
  for (int c = 0; c < NCH; c += 2) {
    const size_t xz1 = oXZ + (size_t)CH * (2 * DINNER);
    const size_t u1  = oU  + (size_t)CH * DINNER;
    const size_t s1  = oS  + (size_t)CH * 96;
    LOAD3(dtB, uB, bvB, cvB, zB, xz1, u1, s1);
    __builtin_amdgcn_sched_barrier(0);
    COMP3(dtA, uA, bvA, cvA, zA, oXZ);
    if (c + 2 < NCH) {
      LOAD3(dtA, uA, bvA, cvA, zA, oXZ + (size_t)(2 * CH) * (2 * DINNER),
            oU + (size_t)(2 * CH) * DINNER, oS + (size_t)(2 * CH) * 96);
      __builtin_amdgcn_sched_barrier(0);
    }
    COMP3(dtB, uB, bvB, cvB, zB, xz1);
    oXZ += (size_t)(2 * CH) * (2 * DINNER);
    oU  += (size_t)(2 * CH) * DINNER;
    oS  += (size_t)(2 * CH) * 96;
  }
}

extern "C" void kernel_launch(void* const* d_in, const int* in_sizes, int n_in,
                              void* d_out, int out_size, void* d_ws, size_t ws_size,
                              hipStream_t stream) {
  const float* x      = (const float*)d_in[0];
  const float* W_in   = (const float*)d_in[1];
  const float* conv_w = (const float*)d_in[2];
  const float* conv_b = (const float*)d_in[3];
  const float* A_log  = (const float*)d_in[4];
  const float* Dp     = (const float*)d_in[5];
  const float* W_x    = (const float*)d_in[6];
  const float* W_dt   = (const float*)d_in[7];
  const float* b_dt   = (const float*)d_in[8];
  const float* W_out  = (const float*)d_in[9];
  float* out = (float*)d_out;

  // workspace layout (total 57.5 MB — unchanged, proven):
  //   xz_bf : ROWS*4096 bf16 = 32 MB  [u_raw|z]; dt over cols 0..2047; gated over z
  //   u_bf  : ROWS*2048 bf16 = 16 MB
  //   xdbl  : ROWS*96  fp32  = 1.5 MB
  //   aprod : 4 MB, hse : 4 MB
  // aliases (time-multiplexed, no extra space):
  //   xb    = u_bf   (8 MB)  x as bf16; dead once conv overwrites u_bf
  //   WinT  = aprod  (8 MB)  W_in^T bf16; dead once scan1 writes aprod/hse
  //   WoutT = u_bf   (4 MB)  W_out^T bf16; built after scan3 (last u reader)
  bf16* xz_bf = (bf16*)d_ws;
  bf16* u_bf  = xz_bf + (size_t)ROWS * 4096;
  float* xdbl = (float*)(u_bf + (size_t)ROWS * DINNER);
  float* aprod = xdbl + (size_t)ROWS * 96;
  float* hse   = aprod + (size_t)B_SZ * SEGS * DINNER * DSTATE;
  bf16* xb    = u_bf;
  bf16* WinT  = (bf16*)aprod;
  bf16* WoutT = u_bf;

  // 0a) xb = bf16(x)
  cvt_f2b_k<<<(ROWS * DMODEL) / (256 * 8), 256, 0, stream>>>(x, xb);
  // 0b) WinT[4096][1024] = bf16(W_in^T)
  transpose_f2b_k<<<dim3((2 * DINNER) / 32, DMODEL / 32), dim3(32, 8), 0, stream>>>(
      W_in, WinT, DMODEL, 2 * DINNER);
  // 1) xz = x @ W_in  (bf16 MFMA, fp32 accum)
  gemm_mfma<bf16><<<dim3((2 * DINNER) / 128, ROWS / 128), 256, 0, stream>>>(
      xb, DMODEL, WinT, DMODEL, xz_bf, 2 * DINNER, DMODEL);
  // 2) u = silu(conv(xz[:, :DINNER]) + conv_b)   (clobbers xb — already consumed)
  conv_silu_k<<<(ROWS * DINNER) / 256, 256, 0, stream>>>(xz_bf, conv_w, conv_b, u_bf);
  // 3) xdbl = u @ W_x  (fp32)
  xdbl_k<<<ROWS / 8, 256, 0, stream>>>(u_bf, W_x, xdbl);
  // 4) dt = softplus(xdbl[:, :64] @ W_dt + b_dt) -> xz cols 0..2047
  gemm128<float, bf16, 1><<<dim3(DINNER / TILE, ROWS / TILE), 256, 0, stream>>>(
      xdbl, 96, W_dt, DINNER, xz_bf, 2 * DINNER, DTRANK, b_dt);
  // 5) segmented scan + gating; gated -> xz cols 2048..4095 (clobbers WinT)
  scan1_k<<<dim3(DINNER / 16, B_SZ * SEGS), 256, 0, stream>>>(
      xz_bf, u_bf, xdbl, A_log, aprod, hse);
  scan2_k<<<dim3(DINNER / 16, B_SZ), 256, 0, stream>>>(aprod, hse);
  scan3_k<<<dim3(DINNER / 16, B_SZ * SEGS), 256, 0, stream>>>(
      xz_bf, u_bf, xdbl, A_log, Dp, hse);
  // 5b) WoutT[1024][2048] = bf16(W_out^T)  (u_bf dead after scan3)
  transpose_f2b_k<<<dim3(DMODEL / 32, DINNER / 32), dim3(32, 8), 0, stream>>>(
      W_out, WoutT, DINNER, DMODEL);
  // 6) out = gated @ W_out  (bf16 MFMA; A = xz cols 2048..4095, lda 4096)
  gemm_mfma<float><<<dim3(DMODEL / 128, ROWS / 128), 256, 0, stream>>>(
      xz_bf + DINNER, 2 * DINNER, WoutT, DINNER, out, DMODEL, DINNER);
}

// Round 8
// 567.066 us; speedup vs baseline: 4.4829x; 1.2339x over previous
//
#include <hip/hip_runtime.h>

#define B_SZ 2
#define L_SZ 2048
#define DMODEL 1024
#define DINNER 2048
#define DSTATE 16
#define DTRANK 64
#define ROWS (B_SZ * L_SZ) /* 4096 */

#define TILE 128
#define BKQ 16

typedef unsigned short bf16;
typedef unsigned short u16x8 __attribute__((ext_vector_type(8)));
typedef short s16x8 __attribute__((ext_vector_type(8)));
typedef float f32x4 __attribute__((ext_vector_type(4)));

__device__ __forceinline__ float bf2f(bf16 s) {
  return __uint_as_float(((unsigned)s) << 16);
}
__device__ __forceinline__ bf16 f2bf(float f) {  // round-to-nearest-even
  unsigned u = __float_as_uint(f);
  unsigned r = u + 0x7FFF + ((u >> 16) & 1);
  return (bf16)(r >> 16);
}
__device__ __forceinline__ float softplus_f(float x) {
  return (x > 20.f) ? x : log1pf(__expf(x));
}
__device__ __forceinline__ float silu_f(float x) {
  return x / (1.f + __expf(-x));
}

// --- A-tile loaders: 8 contiguous elements -> float[8] ---
__device__ __forceinline__ void load8(const float* p, float* r) {
  float4 a0 = *(const float4*)p;
  float4 a1 = *(const float4*)(p + 4);
  r[0] = a0.x; r[1] = a0.y; r[2] = a0.z; r[3] = a0.w;
  r[4] = a1.x; r[5] = a1.y; r[6] = a1.z; r[7] = a1.w;
}

// --- C writers ---
__device__ __forceinline__ void store4(float* C, size_t off, float4 v) {
  *(float4*)&C[off] = v;
}
__device__ __forceinline__ void store4(bf16* C, size_t off, float4 v) {
  ushort4 w;
  w.x = f2bf(v.x); w.y = f2bf(v.y); w.z = f2bf(v.z); w.w = f2bf(v.w);
  *(ushort4*)&C[off] = w;
}
__device__ __forceinline__ void storeC(float* C, size_t off, float v) { C[off] = v; }
__device__ __forceinline__ void storeC(bf16* C, size_t off, float v) { C[off] = f2bf(v); }

// ---------------------------------------------------------------------------
// bf16 MFMA GEMM: C[M x N] = A[M x K] * BT[N x K]^T, fp32 accumulate.
// 128x128 tile, 4 waves of 64x64 (4x4 fragments of 16x16x32). Validated r6/r7.
// ---------------------------------------------------------------------------
#define LSTR 40
template <typename CT>
__global__ __launch_bounds__(256) void gemm_mfma(
    const bf16* __restrict__ A, int lda,
    const bf16* __restrict__ BT, int ldbt,
    CT* __restrict__ C, int ldc, int K) {
  __shared__ alignas(16) bf16 As[128 * LSTR];
  __shared__ alignas(16) bf16 Bs[128 * LSTR];
  const int tid = threadIdx.x;
  const int lane = tid & 63;
  const int wave = tid >> 6;
  const int wm = wave >> 1, wn = wave & 1;
  const int bm = blockIdx.y * 128, bn = blockIdx.x * 128;

  const int sr = tid >> 2;
  const int sq = tid & 3;
  const bf16* Ap0 = A + (size_t)(bm + sr) * lda + sq * 8;
  const bf16* Ap1 = A + (size_t)(bm + sr + 64) * lda + sq * 8;
  const bf16* Bp0 = BT + (size_t)(bn + sr) * ldbt + sq * 8;
  const bf16* Bp1 = BT + (size_t)(bn + sr + 64) * ldbt + sq * 8;
  bf16* wA0 = &As[sr * LSTR + sq * 8];
  bf16* wA1 = &As[(sr + 64) * LSTR + sq * 8];
  bf16* wB0 = &Bs[sr * LSTR + sq * 8];
  bf16* wB1 = &Bs[(sr + 64) * LSTR + sq * 8];

  const int fr = lane & 15;
  const int fq = lane >> 4;
  const bf16* rA = &As[(wm * 64 + fr) * LSTR + fq * 8];
  const bf16* rB = &Bs[(wn * 64 + fr) * LSTR + fq * 8];

  f32x4 acc[4][4];
#pragma unroll
  for (int i = 0; i < 4; ++i)
#pragma unroll
    for (int j = 0; j < 4; ++j) acc[i][j] = (f32x4){0.f, 0.f, 0.f, 0.f};

  for (int k0 = 0; k0 < K; k0 += 32) {
    u16x8 a0 = *(const u16x8*)Ap0;
    u16x8 a1 = *(const u16x8*)Ap1;
    u16x8 b0 = *(const u16x8*)Bp0;
    u16x8 b1 = *(const u16x8*)Bp1;
    __syncthreads();
    *(u16x8*)wA0 = a0;
    *(u16x8*)wA1 = a1;
    *(u16x8*)wB0 = b0;
    *(u16x8*)wB1 = b1;
    __syncthreads();
    s16x8 af[4], bfr[4];
#pragma unroll
    for (int mi = 0; mi < 4; ++mi) af[mi] = *(const s16x8*)(rA + mi * 16 * LSTR);
#pragma unroll
    for (int ni = 0; ni < 4; ++ni) bfr[ni] = *(const s16x8*)(rB + ni * 16 * LSTR);
#pragma unroll
    for (int mi = 0; mi < 4; ++mi)
#pragma unroll
      for (int ni = 0; ni < 4; ++ni)
        acc[mi][ni] = __builtin_amdgcn_mfma_f32_16x16x32_bf16(
            af[mi], bfr[ni], acc[mi][ni], 0, 0, 0);
    Ap0 += 32; Ap1 += 32; Bp0 += 32; Bp1 += 32;
  }

#pragma unroll
  for (int mi = 0; mi < 4; ++mi)
#pragma unroll
    for (int ni = 0; ni < 4; ++ni) {
      const int col = bn + wn * 64 + ni * 16 + fr;
#pragma unroll
      for (int j = 0; j < 4; ++j) {
        const int row = bm + wm * 64 + mi * 16 + fq * 4 + j;
        storeC(C, (size_t)row * ldc + col, acc[mi][ni][j]);
      }
    }
}

// ---------------------------------------------------------------------------
// xdbl = u[4096x2048] @ W_xT[96x2048]^T, split-K MFMA, fp32 atomic combine.
// BM=64, full N=96, SPLITK=8 (K-chunk 256) -> grid (8, 64) = 512 blocks.
// Wave w: rows [bm+16w, bm+16w+16) x 96 cols = 6 n-frags. xdbl pre-zeroed.
// ---------------------------------------------------------------------------
#define XD_SPLITK 8
#define XD_KCH (DINNER / XD_SPLITK) /* 256 */

__global__ __launch_bounds__(256) void xdbl_mfma_k(
    const bf16* __restrict__ u, const bf16* __restrict__ WxT,
    float* __restrict__ xdbl) {
  __shared__ alignas(16) bf16 As[64 * LSTR];
  __shared__ alignas(16) bf16 Bs[96 * LSTR];
  const int tid = threadIdx.x;
  const int lane = tid & 63;
  const int wave = tid >> 6;
  const int bm = blockIdx.y * 64;
  const int k0 = blockIdx.x * XD_KCH;

  // A staging: 64 rows x 32 k = 256 chunks of 8 bf16; thread t -> (t>>2, t&3)
  const int sr = tid >> 2, sq = tid & 3;
  const bf16* Ap = u + (size_t)(bm + sr) * DINNER + k0 + sq * 8;
  bf16* wA = &As[sr * LSTR + sq * 8];
  // B staging: 96 rows x 32 k = 384 chunks; threads 0..191 take chunks t, t+192
  const int c0 = tid, c1 = tid + 192;
  const bf16* Bp0 = WxT + (size_t)(c0 >> 2) * DINNER + k0 + (c0 & 3) * 8;
  const bf16* Bp1 = WxT + (size_t)(c1 >> 2) * DINNER + k0 + (c1 & 3) * 8;
  bf16* wB0 = &Bs[(c0 >> 2) * LSTR + (c0 & 3) * 8];
  bf16* wB1 = &Bs[(c1 >> 2) * LSTR + (c1 & 3) * 8];

  const int fr = lane & 15, fq = lane >> 4;
  const bf16* rA = &As[(wave * 16 + fr) * LSTR + fq * 8];
  const bf16* rB = &Bs[fr * LSTR + fq * 8];

  f32x4 acc[6];
#pragma unroll
  for (int i = 0; i < 6; ++i) acc[i] = (f32x4){0.f, 0.f, 0.f, 0.f};

  for (int kk = 0; kk < XD_KCH; kk += 32) {
    u16x8 a = *(const u16x8*)Ap;
    u16x8 b0, b1;
    if (tid < 192) { b0 = *(const u16x8*)Bp0; b1 = *(const u16x8*)Bp1; }
    __syncthreads();
    *(u16x8*)wA = a;
    if (tid < 192) { *(u16x8*)wB0 = b0; *(u16x8*)wB1 = b1; }
    __syncthreads();
    s16x8 af = *(const s16x8*)rA;
#pragma unroll
    for (int ni = 0; ni < 6; ++ni) {
      s16x8 bfr = *(const s16x8*)(rB + ni * 16 * LSTR);
      acc[ni] = __builtin_amdgcn_mfma_f32_16x16x32_bf16(af, bfr, acc[ni], 0, 0, 0);
    }
    Ap += 32; Bp0 += 32; Bp1 += 32;
  }
#pragma unroll
  for (int ni = 0; ni < 6; ++ni)
#pragma unroll
    for (int j = 0; j < 4; ++j) {
      const int row = bm + wave * 16 + fq * 4 + j;
      atomicAdd(&xdbl[(size_t)row * 96 + ni * 16 + fr], acc[ni][j]);
    }
}

__global__ __launch_bounds__(256) void zero_k(float* __restrict__ p) {
  const size_t i = ((size_t)blockIdx.x * 256 + threadIdx.x) * 4;
  *(float4*)(p + i) = (float4){0.f, 0.f, 0.f, 0.f};
}

// fp32 -> bf16 elementwise (8/thread)
__global__ __launch_bounds__(256) void cvt_f2b_k(
    const float* __restrict__ src, bf16* __restrict__ dst) {
  const size_t i = ((size_t)blockIdx.x * 256 + threadIdx.x) * 8;
  float4 v0 = *(const float4*)(src + i);
  float4 v1 = *(const float4*)(src + i + 4);
  u16x8 o;
  o[0] = f2bf(v0.x); o[1] = f2bf(v0.y); o[2] = f2bf(v0.z); o[3] = f2bf(v0.w);
  o[4] = f2bf(v1.x); o[5] = f2bf(v1.y); o[6] = f2bf(v1.z); o[7] = f2bf(v1.w);
  *(u16x8*)(dst + i) = o;
}

// dst[C][R] (bf16) = transpose(src[R][C] fp32); 32x32 LDS tiles
__global__ __launch_bounds__(256) void transpose_f2b_k(
    const float* __restrict__ src, bf16* __restrict__ dst, int R, int C) {
  __shared__ float t[32][33];
  const int c0 = blockIdx.x * 32, r0 = blockIdx.y * 32;
  const int tx = threadIdx.x, ty = threadIdx.y;
#pragma unroll
  for (int i = 0; i < 4; ++i)
    t[ty + i * 8][tx] = src[(size_t)(r0 + ty + i * 8) * C + c0 + tx];
  __syncthreads();
#pragma unroll
  for (int i = 0; i < 4; ++i)
    dst[(size_t)(c0 + ty + i * 8) * R + r0 + tx] = f2bf(t[tx][ty + i * 8]);
}

// fp32 tiled GEMM (kept for the small dt GEMM, K=64).
template <typename AT, typename CT, int EPI>
__global__ __launch_bounds__(256) void gemm128(
    const AT* __restrict__ A, int lda,
    const float* __restrict__ Bm, int ldb,
    CT* __restrict__ C, int ldc,
    int K, const float* __restrict__ bias) {
  __shared__ float As[BKQ][TILE + 4];
  __shared__ float Bs[BKQ][TILE];
  const int tid = threadIdx.x;
  const int tx = tid & 15, ty = tid >> 4;
  const int bm = blockIdx.y * TILE, bn = blockIdx.x * TILE;
  const int am = tid >> 1, ak = (tid & 1) * 8;
  const int bk = tid >> 4, bc = (tid & 15) * 8;

  const AT* Ap = A + (size_t)(bm + am) * lda + ak;
  const float* Bp = Bm + (size_t)bk * ldb + bn + bc;

  float acc[8][8];
#pragma unroll
  for (int i = 0; i < 8; ++i)
#pragma unroll
    for (int j = 0; j < 8; ++j) acc[i][j] = 0.f;

  for (int k0 = 0; k0 < K; k0 += BKQ) {
    float ar8[8];
    load8(Ap, ar8);
    float4 b0 = *(const float4*)(Bp);
    float4 b1 = *(const float4*)(Bp + 4);
    __syncthreads();
#pragma unroll
    for (int j = 0; j < 8; ++j) As[ak + j][am] = ar8[j];
    *(float4*)&Bs[bk][bc] = b0;
    *(float4*)&Bs[bk][bc + 4] = b1;
    __syncthreads();
#pragma unroll
    for (int k = 0; k < BKQ; ++k) {
      float4 av0 = *(const float4*)&As[k][ty * 4];
      float4 av1 = *(const float4*)&As[k][64 + ty * 4];
      float4 bv0 = *(const float4*)&Bs[k][tx * 4];
      float4 bv1 = *(const float4*)&Bs[k][64 + tx * 4];
      float ar[8] = {av0.x, av0.y, av0.z, av0.w, av1.x, av1.y, av1.z, av1.w};
      float br[8] = {bv0.x, bv0.y, bv0.z, bv0.w, bv1.x, bv1.y, bv1.z, bv1.w};
#pragma unroll
      for (int i = 0; i < 8; ++i)
#pragma unroll
        for (int j = 0; j < 8; ++j)
          acc[i][j] = fmaf(ar[i], br[j], acc[i][j]);
    }
    Ap += BKQ;
    Bp += (size_t)BKQ * ldb;
  }

#pragma unroll
  for (int ih = 0; ih < 2; ++ih)
#pragma unroll
    for (int i = 0; i < 4; ++i) {
      const int row = bm + ih * 64 + ty * 4 + i;
#pragma unroll
      for (int jh = 0; jh < 2; ++jh) {
        const int col = bn + jh * 64 + tx * 4;
        float4 v;
        v.x = acc[ih * 4 + i][jh * 4 + 0];
        v.y = acc[ih * 4 + i][jh * 4 + 1];
        v.z = acc[ih * 4 + i][jh * 4 + 2];
        v.w = acc[ih * 4 + i][jh * 4 + 3];
        if (EPI == 1) {
          v.x = softplus_f(v.x + bias[col + 0]);
          v.y = softplus_f(v.y + bias[col + 1]);
          v.z = softplus_f(v.z + bias[col + 2]);
          v.w = softplus_f(v.w + bias[col + 3]);
        }
        store4(C, (size_t)row * ldc + col, v);
      }
    }
}

// u = silu(causal_depthwise_conv(xz[:, :, :DINNER]) + conv_b), layout (B*L, DINNER)
__global__ __launch_bounds__(256) void conv_silu_k(
    const bf16* __restrict__ xz, const float* __restrict__ w,
    const float* __restrict__ bias, bf16* __restrict__ u) {
  const int idx = blockIdx.x * 256 + threadIdx.x;
  const int d = idx & (DINNER - 1);
  const int row = idx >> 11;
  const int l = row & (L_SZ - 1);
  float s = bias[d];
#pragma unroll
  for (int k = 0; k < 4; ++k) {
    const int t = l - 3 + k;
    if (t >= 0)
      s = fmaf(bf2f(xz[(size_t)(row - 3 + k) * (2 * DINNER) + d]), w[d * 4 + k], s);
  }
  u[idx] = f2bf(silu_f(s));
}

// ---------------------------------------------------------------------------
// Segmented selective scan (3 phases) — unchanged (validated r6/r7).
// ---------------------------------------------------------------------------
#define SEGS 16
#define SEGL (L_SZ / SEGS) /* 128 */
#define CH 8
#define NCH (SEGL / CH) /* 16 */

#define LOAD1(dt_, u_, bv_, oXZ_, oU_, oS_)                                \
  _Pragma("unroll") for (int j = 0; j < CH; ++j) {                         \
    dt_[j] = bf2f(xz[(oXZ_) + (size_t)j * (2 * DINNER)]);                  \
    u_[j]  = bf2f(u[(oU_) + (size_t)j * DINNER]);                         \
    bv_[j] = xdbl[(oS_) + (size_t)j * 96 + 64];                            \
  }

#define COMP1(dt_, u_, bv_)                                                \
  _Pragma("unroll") for (int j = 0; j < CH; ++j) {                         \
    const float abar = __expf(dt_[j] * a);                                 \
    ap *= abar;                                                            \
    h = fmaf(abar, h, dt_[j] * u_[j] * bv_[j]);                            \
  }

__global__ __launch_bounds__(256, 2) void scan1_k(
    const bf16* __restrict__ xz, const bf16* __restrict__ u,
    const float* __restrict__ xdbl, const float* __restrict__ A_log,
    float* __restrict__ aprod, float* __restrict__ hend) {
  const int n = threadIdx.x & 15;
  const int dq = threadIdx.x >> 4;
  const int d = blockIdx.x * 16 + dq;
  const int b = blockIdx.y >> 4;
  const int s = blockIdx.y & (SEGS - 1);
  const float a = -__expf(A_log[n]);
  const size_t t0 = (size_t)b * L_SZ + (size_t)s * SEGL;
  size_t oXZ = t0 * (2 * DINNER) + d;
  size_t oU  = t0 * DINNER + d;
  size_t oS  = t0 * 96 + n;
  float h = 0.f, ap = 1.f;
  float dtA[CH], uA[CH], bvA[CH];
  float dtB[CH], uB[CH], bvB[CH];
  LOAD1(dtA, uA, bvA, oXZ, oU, oS);
  __builtin_amdgcn_sched_barrier(0);
  for (int c = 0; c < NCH; c += 2) {
    LOAD1(dtB, uB, bvB, oXZ + (size_t)CH * (2 * DINNER),
          oU + (size_t)CH * DINNER, oS + (size_t)CH * 96);
    __builtin_amdgcn_sched_barrier(0);
    COMP1(dtA, uA, bvA);
    if (c + 2 < NCH) {
      LOAD1(dtA, uA, bvA, oXZ + (size_t)(2 * CH) * (2 * DINNER),
            oU + (size_t)(2 * CH) * DINNER, oS + (size_t)(2 * CH) * 96);
      __builtin_amdgcn_sched_barrier(0);
    }
    COMP1(dtB, uB, bvB);
    oXZ += (size_t)(2 * CH) * (2 * DINNER);
    oU  += (size_t)(2 * CH) * DINNER;
    oS  += (size_t)(2 * CH) * 96;
  }
  const size_t idx = (((size_t)b * SEGS + s) * DINNER + d) * DSTATE + n;
  aprod[idx] = ap;
  hend[idx]  = h;
}

__global__ __launch_bounds__(256) void scan2_k(
    const float* __restrict__ aprod, float* hse) {
  const int n = threadIdx.x & 15;
  const int dq = threadIdx.x >> 4;
  const int d = blockIdx.x * 16 + dq;
  const int b = blockIdx.y;
  const size_t base = ((size_t)b * SEGS * DINNER + d) * DSTATE + n;
  float av[SEGS], ev[SEGS];
#pragma unroll
  for (int s = 0; s < SEGS; ++s) {
    av[s] = aprod[base + (size_t)s * DINNER * DSTATE];
    ev[s] = hse[base + (size_t)s * DINNER * DSTATE];
  }
  float h = 0.f;
#pragma unroll
  for (int s = 0; s < SEGS; ++s) {
    hse[base + (size_t)s * DINNER * DSTATE] = h;
    h = fmaf(av[s], h, ev[s]);
  }
}

#define LOAD3(dt_, u_, bv_, cv_, z_, oXZ_, oU_, oS_)                       \
  _Pragma("unroll") for (int j = 0; j < CH; ++j) {                         \
    dt_[j] = bf2f(xz[(oXZ_) + (size_t)j * (2 * DINNER)]);                  \
    z_[j]  = bf2f(xz[(oXZ_) + (size_t)j * (2 * DINNER) + DINNER]);         \
    u_[j]  = bf2f(u[(oU_) + (size_t)j * DINNER]);                         \
    bv_[j] = xdbl[(oS_) + (size_t)j * 96 + 64];                            \
    cv_[j] = xdbl[(oS_) + (size_t)j * 96 + 80];                            \
  }

#define COMP3(dt_, u_, bv_, cv_, z_, oXZ_)                                 \
  _Pragma("unroll") for (int j = 0; j < CH; ++j) {                         \
    const float abar = __expf(dt_[j] * a);                                 \
    h = fmaf(abar, h, dt_[j] * u_[j] * bv_[j]);                            \
    float p = h * cv_[j];                                                  \
    p += __shfl_xor(p, 1, 16);                                             \
    p += __shfl_xor(p, 2, 16);                                             \
    p += __shfl_xor(p, 4, 16);                                             \
    p += __shfl_xor(p, 8, 16);                                             \
    const float y = fmaf(Dd, u_[j], p);                                    \
    const float g = y * silu_f(z_[j]);                                     \
    if (n == 0)                                                            \
      xz[(oXZ_) + (size_t)j * (2 * DINNER) + DINNER] = f2bf(g);            \
  }

__global__ __launch_bounds__(256, 2) void scan3_k(
    bf16* xz /* dt | z->gated */, const bf16* __restrict__ u,
    const float* __restrict__ xdbl, const float* __restrict__ A_log,
    const float* __restrict__ Dp, const float* __restrict__ hstart) {
  const int n = threadIdx.x & 15;
  const int dq = threadIdx.x >> 4;
  const int d = blockIdx.x * 16 + dq;
  const int b = blockIdx.y >> 4;
  const int s = blockIdx.y & (SEGS - 1);
  const float a = -__expf(A_log[n]);
  const float Dd = Dp[d];
  float h = hstart[(((size_t)b * SEGS + s) * DINNER + d) * DSTATE + n];

  const size_t t0 = (size_t)b * L_SZ + (size_t)s * SEGL;
  size_t oXZ = t0 * (2 * DINNER) + d;
  size_t oU  = t0 * DINNER + d;
  size_t oS  = t0 * 96 + n;

  float dtA[CH], uA[CH], bvA[CH], cvA[CH], zA[CH];
  float dtB[CH], uB[CH], bvB[CH], cvB[CH], zB[CH];

  LOAD3(dtA, uA, bvA, cvA, zA, oXZ, oU, oS);
  __builtin_amdgcn_sched_barrier(0);
  for (int c = 0; c < NCH; c += 2) {
    const size_t xz1 = oXZ + (size_t)CH * (2 * DINNER);
    const size_t u1  = oU  + (size_t)CH * DINNER;
    const size_t s1  = oS  + (size_t)CH * 96;
    LOAD3(dtB, uB, bvB, cvB, zB, xz1, u1, s1);
    __builtin_amdgcn_sched_barrier(0);
    COMP3(dtA, uA, bvA, cvA, zA, oXZ);
    if (c + 2 < NCH) {
      LOAD3(dtA, uA, bvA, cvA, zA, oXZ + (size_t)(2 * CH) * (2 * DINNER),
            oU + (size_t)(2 * CH) * DINNER, oS + (size_t)(2 * CH) * 96);
      __builtin_amdgcn_sched_barrier(0);
    }
    COMP3(dtB, uB, bvB, cvB, zB, xz1);
    oXZ += (size_t)(2 * CH) * (2 * DINNER);
    oU  += (size_t)(2 * CH) * DINNER;
    oS  += (size_t)(2 * CH) * 96;
  }
}

extern "C" void kernel_launch(void* const* d_in, const int* in_sizes, int n_in,
                              void* d_out, int out_size, void* d_ws, size_t ws_size,
                              hipStream_t stream) {
  const float* x      = (const float*)d_in[0];
  const float* W_in   = (const float*)d_in[1];
  const float* conv_w = (const float*)d_in[2];
  const float* conv_b = (const float*)d_in[3];
  const float* A_log  = (const float*)d_in[4];
  const float* Dp     = (const float*)d_in[5];
  const float* W_x    = (const float*)d_in[6];
  const float* W_dt   = (const float*)d_in[7];
  const float* b_dt   = (const float*)d_in[8];
  const float* W_out  = (const float*)d_in[9];
  float* out = (float*)d_out;

  // workspace layout (total 57.5 MB — unchanged, proven):
  //   xz_bf : 32 MB  [u_raw|z]; dt over cols 0..2047; gated over z
  //   u_bf  : 16 MB
  //   xdbl  : 1.5 MB
  //   aprod : 4 MB, hse : 4 MB
  // aliases (time-multiplexed):
  //   xb    = u_bf   x as bf16; dead once conv overwrites u_bf
  //   WinT  = aprod  W_in^T bf16 (8 MB over aprod+hse); dead after gemm1
  //   WxT   = aprod  W_x^T bf16 (384 KB); built after gemm1, dead before scan1
  //   WoutT = u_bf   W_out^T bf16; built after scan3 (last u reader)
  bf16* xz_bf = (bf16*)d_ws;
  bf16* u_bf  = xz_bf + (size_t)ROWS * 4096;
  float* xdbl = (float*)(u_bf + (size_t)ROWS * DINNER);
  float* aprod = xdbl + (size_t)ROWS * 96;
  float* hse   = aprod + (size_t)B_SZ * SEGS * DINNER * DSTATE;
  bf16* xb    = u_bf;
  bf16* WinT  = (bf16*)aprod;
  bf16* WxT   = (bf16*)aprod;
  bf16* WoutT = u_bf;

  // 0a) xb = bf16(x)
  cvt_f2b_k<<<(ROWS * DMODEL) / (256 * 8), 256, 0, stream>>>(x, xb);
  // 0b) WinT[4096][1024] = bf16(W_in^T)
  transpose_f2b_k<<<dim3((2 * DINNER) / 32, DMODEL / 32), dim3(32, 8), 0, stream>>>(
      W_in, WinT, DMODEL, 2 * DINNER);
  // 1) xz = x @ W_in  (bf16 MFMA)
  gemm_mfma<bf16><<<dim3((2 * DINNER) / 128, ROWS / 128), 256, 0, stream>>>(
      xb, DMODEL, WinT, DMODEL, xz_bf, 2 * DINNER, DMODEL);
  // 2) u = silu(conv(xz[:, :DINNER]) + conv_b)   (clobbers xb)
  conv_silu_k<<<(ROWS * DINNER) / 256, 256, 0, stream>>>(xz_bf, conv_w, conv_b, u_bf);
  // 3) xdbl = u @ W_x  (split-K MFMA, atomic fp32 combine)
  zero_k<<<(ROWS * 96) / (256 * 4), 256, 0, stream>>>(xdbl);
  transpose_f2b_k<<<dim3(96 / 32, DINNER / 32), dim3(32, 8), 0, stream>>>(
      W_x, WxT, DINNER, 96);
  xdbl_mfma_k<<<dim3(XD_SPLITK, ROWS / 64), 256, 0, stream>>>(u_bf, WxT, xdbl);
  // 4) dt = softplus(xdbl[:, :64] @ W_dt + b_dt) -> xz cols 0..2047
  gemm128<float, bf16, 1><<<dim3(DINNER / TILE, ROWS / TILE), 256, 0, stream>>>(
      xdbl, 96, W_dt, DINNER, xz_bf, 2 * DINNER, DTRANK, b_dt);
  // 5) segmented scan + gating; gated -> xz cols 2048..4095 (clobbers WxT)
  scan1_k<<<dim3(DINNER / 16, B_SZ * SEGS), 256, 0, stream>>>(
      xz_bf, u_bf, xdbl, A_log, aprod, hse);
  scan2_k<<<dim3(DINNER / 16, B_SZ), 256, 0, stream>>>(aprod, hse);
  scan3_k<<<dim3(DINNER / 16, B_SZ * SEGS), 256, 0, stream>>>(
      xz_bf, u_bf, xdbl, A_log, Dp, hse);
  // 5b) WoutT[1024][2048] = bf16(W_out^T)  (u_bf dead after scan3)
  transpose_f2b_k<<<dim3(DMODEL / 32, DINNER / 32), dim3(32, 8), 0, stream>>>(
      W_out, WoutT, DINNER, DMODEL);
  // 6) out = gated @ W_out  (bf16 MFMA; A = xz cols 2048..4095, lda 4096)
  gemm_mfma<float><<<dim3(DMODEL / 128, ROWS / 128), 256, 0, stream>>>(
      xz_bf + DINNER, 2 * DINNER, WoutT, DINNER, out, DMODEL, DINNER);
}

// Round 10
// 398.307 us; speedup vs baseline: 6.3822x; 1.4237x over previous
//
#include <hip/hip_runtime.h>

#define B_SZ 2
#define L_SZ 2048
#define DMODEL 1024
#define DINNER 2048
#define DSTATE 16
#define DTRANK 64
#define ROWS (B_SZ * L_SZ) /* 4096 */

#define TILE 128
#define BKQ 16

typedef unsigned short bf16;
typedef unsigned short u16x8 __attribute__((ext_vector_type(8)));
typedef short s16x8 __attribute__((ext_vector_type(8)));
typedef float f32x4 __attribute__((ext_vector_type(4)));

__device__ __forceinline__ float bf2f(bf16 s) {
  return __uint_as_float(((unsigned)s) << 16);
}
__device__ __forceinline__ bf16 f2bf(float f) {  // round-to-nearest-even
  unsigned u = __float_as_uint(f);
  unsigned r = u + 0x7FFF + ((u >> 16) & 1);
  return (bf16)(r >> 16);
}
__device__ __forceinline__ float softplus_f(float x) {
  return (x > 20.f) ? x : log1pf(__expf(x));
}
__device__ __forceinline__ float silu_f(float x) {
  return x / (1.f + __expf(-x));
}

// --- A-tile loaders: 8 contiguous elements -> float[8] ---
__device__ __forceinline__ void load8(const float* p, float* r) {
  float4 a0 = *(const float4*)p;
  float4 a1 = *(const float4*)(p + 4);
  r[0] = a0.x; r[1] = a0.y; r[2] = a0.z; r[3] = a0.w;
  r[4] = a1.x; r[5] = a1.y; r[6] = a1.z; r[7] = a1.w;
}

// --- C writers ---
__device__ __forceinline__ void store4(float* C, size_t off, float4 v) {
  *(float4*)&C[off] = v;
}
__device__ __forceinline__ void store4(bf16* C, size_t off, float4 v) {
  ushort4 w;
  w.x = f2bf(v.x); w.y = f2bf(v.y); w.z = f2bf(v.z); w.w = f2bf(v.w);
  *(ushort4*)&C[off] = w;
}
__device__ __forceinline__ void storeC(float* C, size_t off, float v) { C[off] = v; }
__device__ __forceinline__ void storeC(bf16* C, size_t off, float v) { C[off] = f2bf(v); }

// ---------------------------------------------------------------------------
// bf16 MFMA GEMM: C[M x N] = A[M x K] * BT[N x K]^T, fp32 accumulate.
// 128x128 tile, 4 waves of 64x64 (4x4 fragments of 16x16x32). Validated r6-r8.
// ---------------------------------------------------------------------------
#define LSTR 40
template <typename CT>
__global__ __launch_bounds__(256) void gemm_mfma(
    const bf16* __restrict__ A, int lda,
    const bf16* __restrict__ BT, int ldbt,
    CT* __restrict__ C, int ldc, int K) {
  __shared__ alignas(16) bf16 As[128 * LSTR];
  __shared__ alignas(16) bf16 Bs[128 * LSTR];
  const int tid = threadIdx.x;
  const int lane = tid & 63;
  const int wave = tid >> 6;
  const int wm = wave >> 1, wn = wave & 1;
  const int bm = blockIdx.y * 128, bn = blockIdx.x * 128;

  const int sr = tid >> 2;
  const int sq = tid & 3;
  const bf16* Ap0 = A + (size_t)(bm + sr) * lda + sq * 8;
  const bf16* Ap1 = A + (size_t)(bm + sr + 64) * lda + sq * 8;
  const bf16* Bp0 = BT + (size_t)(bn + sr) * ldbt + sq * 8;
  const bf16* Bp1 = BT + (size_t)(bn + sr + 64) * ldbt + sq * 8;
  bf16* wA0 = &As[sr * LSTR + sq * 8];
  bf16* wA1 = &As[(sr + 64) * LSTR + sq * 8];
  bf16* wB0 = &Bs[sr * LSTR + sq * 8];
  bf16* wB1 = &Bs[(sr + 64) * LSTR + sq * 8];

  const int fr = lane & 15;
  const int fq = lane >> 4;
  const bf16* rA = &As[(wm * 64 + fr) * LSTR + fq * 8];
  const bf16* rB = &Bs[(wn * 64 + fr) * LSTR + fq * 8];

  f32x4 acc[4][4];
#pragma unroll
  for (int i = 0; i < 4; ++i)
#pragma unroll
    for (int j = 0; j < 4; ++j) acc[i][j] = (f32x4){0.f, 0.f, 0.f, 0.f};

  for (int k0 = 0; k0 < K; k0 += 32) {
    u16x8 a0 = *(const u16x8*)Ap0;
    u16x8 a1 = *(const u16x8*)Ap1;
    u16x8 b0 = *(const u16x8*)Bp0;
    u16x8 b1 = *(const u16x8*)Bp1;
    __syncthreads();
    *(u16x8*)wA0 = a0;
    *(u16x8*)wA1 = a1;
    *(u16x8*)wB0 = b0;
    *(u16x8*)wB1 = b1;
    __syncthreads();
    s16x8 af[4], bfr[4];
#pragma unroll
    for (int mi = 0; mi < 4; ++mi) af[mi] = *(const s16x8*)(rA + mi * 16 * LSTR);
#pragma unroll
    for (int ni = 0; ni < 4; ++ni) bfr[ni] = *(const s16x8*)(rB + ni * 16 * LSTR);
#pragma unroll
    for (int mi = 0; mi < 4; ++mi)
#pragma unroll
      for (int ni = 0; ni < 4; ++ni)
        acc[mi][ni] = __builtin_amdgcn_mfma_f32_16x16x32_bf16(
            af[mi], bfr[ni], acc[mi][ni], 0, 0, 0);
    Ap0 += 32; Ap1 += 32; Bp0 += 32; Bp1 += 32;
  }

#pragma unroll
  for (int mi = 0; mi < 4; ++mi)
#pragma unroll
    for (int ni = 0; ni < 4; ++ni) {
      const int col = bn + wn * 64 + ni * 16 + fr;
#pragma unroll
      for (int j = 0; j < 4; ++j) {
        const int row = bm + wm * 64 + mi * 16 + fq * 4 + j;
        storeC(C, (size_t)row * ldc + col, acc[mi][ni][j]);
      }
    }
}

// ---------------------------------------------------------------------------
// xdbl = u @ W_xT^T, split-K MFMA, fp32 atomic combine. Validated r8.
// ---------------------------------------------------------------------------
#define XD_SPLITK 8
#define XD_KCH (DINNER / XD_SPLITK) /* 256 */

__global__ __launch_bounds__(256) void xdbl_mfma_k(
    const bf16* __restrict__ u, const bf16* __restrict__ WxT,
    float* __restrict__ xdbl) {
  __shared__ alignas(16) bf16 As[64 * LSTR];
  __shared__ alignas(16) bf16 Bs[96 * LSTR];
  const int tid = threadIdx.x;
  const int lane = tid & 63;
  const int wave = tid >> 6;
  const int bm = blockIdx.y * 64;
  const int k0 = blockIdx.x * XD_KCH;

  const int sr = tid >> 2, sq = tid & 3;
  const bf16* Ap = u + (size_t)(bm + sr) * DINNER + k0 + sq * 8;
  bf16* wA = &As[sr * LSTR + sq * 8];
  const int c0 = tid, c1 = tid + 192;
  const bf16* Bp0 = WxT + (size_t)(c0 >> 2) * DINNER + k0 + (c0 & 3) * 8;
  const bf16* Bp1 = WxT + (size_t)(c1 >> 2) * DINNER + k0 + (c1 & 3) * 8;
  bf16* wB0 = &Bs[(c0 >> 2) * LSTR + (c0 & 3) * 8];
  bf16* wB1 = &Bs[(c1 >> 2) * LSTR + (c1 & 3) * 8];

  const int fr = lane & 15, fq = lane >> 4;
  const bf16* rA = &As[(wave * 16 + fr) * LSTR + fq * 8];
  const bf16* rB = &Bs[fr * LSTR + fq * 8];

  f32x4 acc[6];
#pragma unroll
  for (int i = 0; i < 6; ++i) acc[i] = (f32x4){0.f, 0.f, 0.f, 0.f};

  for (int kk = 0; kk < XD_KCH; kk += 32) {
    u16x8 a = *(const u16x8*)Ap;
    u16x8 b0, b1;
    if (tid < 192) { b0 = *(const u16x8*)Bp0; b1 = *(const u16x8*)Bp1; }
    __syncthreads();
    *(u16x8*)wA = a;
    if (tid < 192) { *(u16x8*)wB0 = b0; *(u16x8*)wB1 = b1; }
    __syncthreads();
    s16x8 af = *(const s16x8*)rA;
#pragma unroll
    for (int ni = 0; ni < 6; ++ni) {
      s16x8 bfr = *(const s16x8*)(rB + ni * 16 * LSTR);
      acc[ni] = __builtin_amdgcn_mfma_f32_16x16x32_bf16(af, bfr, acc[ni], 0, 0, 0);
    }
    Ap += 32; Bp0 += 32; Bp1 += 32;
  }
#pragma unroll
  for (int ni = 0; ni < 6; ++ni)
#pragma unroll
    for (int j = 0; j < 4; ++j) {
      const int row = bm + wave * 16 + fq * 4 + j;
      atomicAdd(&xdbl[(size_t)row * 96 + ni * 16 + fr], acc[ni][j]);
    }
}

__global__ __launch_bounds__(256) void zero_k(float* __restrict__ p) {
  const size_t i = ((size_t)blockIdx.x * 256 + threadIdx.x) * 4;
  *(float4*)(p + i) = (float4){0.f, 0.f, 0.f, 0.f};
}

// fp32 -> bf16 elementwise (8/thread)
__global__ __launch_bounds__(256) void cvt_f2b_k(
    const float* __restrict__ src, bf16* __restrict__ dst) {
  const size_t i = ((size_t)blockIdx.x * 256 + threadIdx.x) * 8;
  float4 v0 = *(const float4*)(src + i);
  float4 v1 = *(const float4*)(src + i + 4);
  u16x8 o;
  o[0] = f2bf(v0.x); o[1] = f2bf(v0.y); o[2] = f2bf(v0.z); o[3] = f2bf(v0.w);
  o[4] = f2bf(v1.x); o[5] = f2bf(v1.y); o[6] = f2bf(v1.z); o[7] = f2bf(v1.w);
  *(u16x8*)(dst + i) = o;
}

// dst[C][R] (bf16) = transpose(src[R][C] fp32); 32x32 LDS tiles
__global__ __launch_bounds__(256) void transpose_f2b_k(
    const float* __restrict__ src, bf16* __restrict__ dst, int R, int C) {
  __shared__ float t[32][33];
  const int c0 = blockIdx.x * 32, r0 = blockIdx.y * 32;
  const int tx = threadIdx.x, ty = threadIdx.y;
#pragma unroll
  for (int i = 0; i < 4; ++i)
    t[ty + i * 8][tx] = src[(size_t)(r0 + ty + i * 8) * C + c0 + tx];
  __syncthreads();
#pragma unroll
  for (int i = 0; i < 4; ++i)
    dst[(size_t)(c0 + ty + i * 8) * R + r0 + tx] = f2bf(t[tx][ty + i * 8]);
}

// fp32 tiled GEMM (kept for the small dt GEMM, K=64).
template <typename AT, typename CT, int EPI>
__global__ __launch_bounds__(256) void gemm128(
    const AT* __restrict__ A, int lda,
    const float* __restrict__ Bm, int ldb,
    CT* __restrict__ C, int ldc,
    int K, const float* __restrict__ bias) {
  __shared__ float As[BKQ][TILE + 4];
  __shared__ float Bs[BKQ][TILE];
  const int tid = threadIdx.x;
  const int tx = tid & 15, ty = tid >> 4;
  const int bm = blockIdx.y * TILE, bn = blockIdx.x * TILE;
  const int am = tid >> 1, ak = (tid & 1) * 8;
  const int bk = tid >> 4, bc = (tid & 15) * 8;

  const AT* Ap = A + (size_t)(bm + am) * lda + ak;
  const float* Bp = Bm + (size_t)bk * ldb + bn + bc;

  float acc[8][8];
#pragma unroll
  for (int i = 0; i < 8; ++i)
#pragma unroll
    for (int j = 0; j < 8; ++j) acc[i][j] = 0.f;

  for (int k0 = 0; k0 < K; k0 += BKQ) {
    float ar8[8];
    load8(Ap, ar8);
    float4 b0 = *(const float4*)(Bp);
    float4 b1 = *(const float4*)(Bp + 4);
    __syncthreads();
#pragma unroll
    for (int j = 0; j < 8; ++j) As[ak + j][am] = ar8[j];
    *(float4*)&Bs[bk][bc] = b0;
    *(float4*)&Bs[bk][bc + 4] = b1;
    __syncthreads();
#pragma unroll
    for (int k = 0; k < BKQ; ++k) {
      float4 av0 = *(const float4*)&As[k][ty * 4];
      float4 av1 = *(const float4*)&As[k][64 + ty * 4];
      float4 bv0 = *(const float4*)&Bs[k][tx * 4];
      float4 bv1 = *(const float4*)&Bs[k][64 + tx * 4];
      float ar[8] = {av0.x, av0.y, av0.z, av0.w, av1.x, av1.y, av1.z, av1.w};
      float br[8] = {bv0.x, bv0.y, bv0.z, bv0.w, bv1.x, bv1.y, bv1.z, bv1.w};
#pragma unroll
      for (int i = 0; i < 8; ++i)
#pragma unroll
        for (int j = 0; j < 8; ++j)
          acc[i][j] = fmaf(ar[i], br[j], acc[i][j]);
    }
    Ap += BKQ;
    Bp += (size_t)BKQ * ldb;
  }

#pragma unroll
  for (int ih = 0; ih < 2; ++ih)
#pragma unroll
    for (int i = 0; i < 4; ++i) {
      const int row = bm + ih * 64 + ty * 4 + i;
#pragma unroll
      for (int jh = 0; jh < 2; ++jh) {
        const int col = bn + jh * 64 + tx * 4;
        float4 v;
        v.x = acc[ih * 4 + i][jh * 4 + 0];
        v.y = acc[ih * 4 + i][jh * 4 + 1];
        v.z = acc[ih * 4 + i][jh * 4 + 2];
        v.w = acc[ih * 4 + i][jh * 4 + 3];
        if (EPI == 1) {
          v.x = softplus_f(v.x + bias[col + 0]);
          v.y = softplus_f(v.y + bias[col + 1]);
          v.z = softplus_f(v.z + bias[col + 2]);
          v.w = softplus_f(v.w + bias[col + 3]);
        }
        store4(C, (size_t)row * ldc + col, v);
      }
    }
}

// u = silu(causal_depthwise_conv(xz[:, :, :DINNER]) + conv_b), layout (B*L, DINNER)
__global__ __launch_bounds__(256) void conv_silu_k(
    const bf16* __restrict__ xz, const float* __restrict__ w,
    const float* __restrict__ bias, bf16* __restrict__ u) {
  const int idx = blockIdx.x * 256 + threadIdx.x;
  const int d = idx & (DINNER - 1);
  const int row = idx >> 11;
  const int l = row & (L_SZ - 1);
  float s = bias[d];
#pragma unroll
  for (int k = 0; k < 4; ++k) {
    const int t = l - 3 + k;
    if (t >= 0)
      s = fmaf(bf2f(xz[(size_t)(row - 3 + k) * (2 * DINNER) + d]), w[d * 4 + k], s);
  }
  u[idx] = f2bf(silu_f(s));
}

// ---------------------------------------------------------------------------
// Segmented selective scan, THREAD-PER-CHANNEL (r8 was VALU-issue-bound:
// 16 lanes/d redundantly computed shared work + 4-shfl butterfly per t).
// Now: thread = one d; h[16],a[16] in regs; B/C (depend on (b,t) only) staged
// in LDS per block (broadcast reads); dt/u/z lane-coalesced; n-reduction =
// in-register fmaf chain (zero shuffles); gating computed once, all lanes
// store (coalesced). SEGS=32 (8 waves/CU); summaries bf16 (ws stays ~57.9MB).
// ---------------------------------------------------------------------------
#define SEGS 32
#define SEGL (L_SZ / SEGS) /* 64 */
#define SCH 8
#define SNCH (SEGL / SCH) /* 8 */

#define S1LOAD(dt_, u_, tb_)                                               \
  _Pragma("unroll") for (int j = 0; j < SCH; ++j) {                        \
    dt_[j] = bf2f(xz[oX + (size_t)((tb_) + j) * (2 * DINNER)]);            \
    u_[j]  = bf2f(u[oU + (size_t)((tb_) + j) * DINNER]);                   \
  }

#define S1COMP(dt_, u_, tb_)                                               \
  _Pragma("unroll") for (int j = 0; j < SCH; ++j) {                        \
    const float dtv = dt_[j];                                              \
    const float x = dtv * u_[j];                                           \
    float bb[16];                                                          \
    *(float4*)&bb[0]  = *(const float4*)&Bv[(tb_) + j][0];                 \
    *(float4*)&bb[4]  = *(const float4*)&Bv[(tb_) + j][4];                 \
    *(float4*)&bb[8]  = *(const float4*)&Bv[(tb_) + j][8];                 \
    *(float4*)&bb[12] = *(const float4*)&Bv[(tb_) + j][12];                \
    _Pragma("unroll") for (int n = 0; n < 16; ++n) {                       \
      const float abar = __expf(dtv * a[n]);                               \
      ap[n] *= abar;                                                       \
      h[n] = fmaf(abar, h[n], x * bb[n]);                                  \
    }                                                                      \
  }

__global__ __launch_bounds__(256) void scan1_k(
    const bf16* __restrict__ xz, const bf16* __restrict__ u,
    const float* __restrict__ xdbl, const float* __restrict__ A_log,
    bf16* __restrict__ aprod, bf16* __restrict__ hend) {
  __shared__ float Bv[SEGL][16];
  const int tid = threadIdx.x;
  const int d = blockIdx.x * 256 + tid;
  const int b = blockIdx.y >> 5;            // SEGS == 32
  const int s = blockIdx.y & (SEGS - 1);
  const int t0 = b * L_SZ + s * SEGL;
  {  // stage B: SEGL*16 = 1024 floats, one float4 per thread
    const int tr = tid >> 2, q = tid & 3;
    *(float4*)&Bv[tr][q * 4] =
        *(const float4*)&xdbl[(size_t)(t0 + tr) * 96 + 64 + q * 4];
  }
  float a[16];
#pragma unroll
  for (int n = 0; n < 16; ++n) a[n] = -__expf(A_log[n]);
  float h[16], ap[16];
#pragma unroll
  for (int n = 0; n < 16; ++n) { h[n] = 0.f; ap[n] = 1.f; }

  const size_t oX = (size_t)t0 * (2 * DINNER) + d;
  const size_t oU = (size_t)t0 * DINNER + d;
  float dtA[SCH], uA[SCH], dtB[SCH], uB[SCH];
  S1LOAD(dtA, uA, 0);
  __builtin_amdgcn_sched_barrier(0);
  __syncthreads();
  for (int c = 0; c < SNCH; c += 2) {
    S1LOAD(dtB, uB, (c + 1) * SCH);
    __builtin_amdgcn_sched_barrier(0);
    S1COMP(dtA, uA, c * SCH);
    if (c + 2 < SNCH) {
      S1LOAD(dtA, uA, (c + 2) * SCH);
      __builtin_amdgcn_sched_barrier(0);
    }
    S1COMP(dtB, uB, (c + 1) * SCH);
  }
  const size_t ob = ((size_t)(b * SEGS + s) * DSTATE) * DINNER + d;
#pragma unroll
  for (int n = 0; n < 16; ++n) {
    aprod[ob + (size_t)n * DINNER] = f2bf(ap[n]);
    hend[ob + (size_t)n * DINNER]  = f2bf(h[n]);
  }
}

// scan2: hse in = h_end per segment, out = h_start. thread = (b,n,d).
__global__ __launch_bounds__(256) void scan2_k(
    const bf16* __restrict__ aprod, bf16* hse) {
  const int tid = threadIdx.x;
  const int d = blockIdx.x * 256 + tid;
  const int b = blockIdx.y >> 4;            // DSTATE == 16
  const int n = blockIdx.y & 15;
  const size_t base = ((size_t)b * SEGS * DSTATE + n) * DINNER + d;
  const size_t str = (size_t)DSTATE * DINNER;
  float av[SEGS], ev[SEGS];
#pragma unroll
  for (int s = 0; s < SEGS; ++s) {
    av[s] = bf2f(aprod[base + (size_t)s * str]);
    ev[s] = bf2f(hse[base + (size_t)s * str]);
  }
  float h = 0.f;
#pragma unroll
  for (int s = 0; s < SEGS; ++s) {
    hse[base + (size_t)s * str] = f2bf(h);
    h = fmaf(av[s], h, ev[s]);
  }
}

#define S3LOAD(dt_, u_, z_, tb_)                                           \
  _Pragma("unroll") for (int j = 0; j < SCH; ++j) {                        \
    dt_[j] = bf2f(xz[oX + (size_t)((tb_) + j) * (2 * DINNER)]);            \
    z_[j]  = bf2f(xz[oX + (size_t)((tb_) + j) * (2 * DINNER) + DINNER]);   \
    u_[j]  = bf2f(u[oU + (size_t)((tb_) + j) * DINNER]);                   \
  }

#define S3COMP(dt_, u_, z_, tb_)                                           \
  _Pragma("unroll") for (int j = 0; j < SCH; ++j) {                        \
    const float dtv = dt_[j];                                              \
    const float uv = u_[j];                                                \
    const float x = dtv * uv;                                              \
    float bb[16], cc[16];                                                  \
    *(float4*)&bb[0]  = *(const float4*)&BC[(tb_) + j][0];                 \
    *(float4*)&bb[4]  = *(const float4*)&BC[(tb_) + j][4];                 \
    *(float4*)&bb[8]  = *(const float4*)&BC[(tb_) + j][8];                 \
    *(float4*)&bb[12] = *(const float4*)&BC[(tb_) + j][12];                \
    *(float4*)&cc[0]  = *(const float4*)&BC[(tb_) + j][16];                \
    *(float4*)&cc[4]  = *(const float4*)&BC[(tb_) + j][20];                \
    *(float4*)&cc[8]  = *(const float4*)&BC[(tb_) + j][24];                \
    *(float4*)&cc[12] = *(const float4*)&BC[(tb_) + j][28];                \
    float p = 0.f;                                                         \
    _Pragma("unroll") for (int n = 0; n < 16; ++n) {                       \
      const float abar = __expf(dtv * a[n]);                               \
      h[n] = fmaf(abar, h[n], x * bb[n]);                                  \
      p = fmaf(h[n], cc[n], p);                                            \
    }                                                                      \
    const float y = fmaf(Dd, uv, p);                                       \
    xz[oX + (size_t)((tb_) + j) * (2 * DINNER) + DINNER] =                 \
        f2bf(y * silu_f(z_[j]));                                           \
  }

__global__ __launch_bounds__(256) void scan3_k(
    bf16* xz /* dt | z->gated */, const bf16* __restrict__ u,
    const float* __restrict__ xdbl, const float* __restrict__ A_log,
    const float* __restrict__ Dp, const bf16* __restrict__ hstart) {
  __shared__ float BC[SEGL][32];
  const int tid = threadIdx.x;
  const int d = blockIdx.x * 256 + tid;
  const int b = blockIdx.y >> 5;
  const int s = blockIdx.y & (SEGS - 1);
  const int t0 = b * L_SZ + s * SEGL;
  {  // stage B||C: SEGL*32 = 2048 floats, two float4 per thread
    const int s0 = tid * 2;
#pragma unroll
    for (int k = 0; k < 2; ++k) {
      const int sl = s0 + k;
      const int tr = sl >> 3, q = sl & 7;
      *(float4*)&BC[tr][q * 4] =
          *(const float4*)&xdbl[(size_t)(t0 + tr) * 96 + 64 + q * 4];
    }
  }
  float a[16];
#pragma unroll
  for (int n = 0; n < 16; ++n) a[n] = -__expf(A_log[n]);
  const float Dd = Dp[d];
  const size_t ob = ((size_t)(b * SEGS + s) * DSTATE) * DINNER + d;
  float h[16];
#pragma unroll
  for (int n = 0; n < 16; ++n) h[n] = bf2f(hstart[ob + (size_t)n * DINNER]);

  const size_t oX = (size_t)t0 * (2 * DINNER) + d;
  const size_t oU = (size_t)t0 * DINNER + d;
  float dtA[SCH], uA[SCH], zA[SCH], dtB[SCH], uB[SCH], zB[SCH];
  S3LOAD(dtA, uA, zA, 0);
  __builtin_amdgcn_sched_barrier(0);
  __syncthreads();
  for (int c = 0; c < SNCH; c += 2) {
    S3LOAD(dtB, uB, zB, (c + 1) * SCH);
    __builtin_amdgcn_sched_barrier(0);
    S3COMP(dtA, uA, zA, c * SCH);
    if (c + 2 < SNCH) {
      S3LOAD(dtA, uA, zA, (c + 2) * SCH);
      __builtin_amdgcn_sched_barrier(0);
    }
    S3COMP(dtB, uB, zB, (c + 1) * SCH);
  }
}

extern "C" void kernel_launch(void* const* d_in, const int* in_sizes, int n_in,
                              void* d_out, int out_size, void* d_ws, size_t ws_size,
                              hipStream_t stream) {
  const float* x      = (const float*)d_in[0];
  const float* W_in   = (const float*)d_in[1];
  const float* conv_w = (const float*)d_in[2];
  const float* conv_b = (const float*)d_in[3];
  const float* A_log  = (const float*)d_in[4];
  const float* Dp     = (const float*)d_in[5];
  const float* W_x    = (const float*)d_in[6];
  const float* W_dt   = (const float*)d_in[7];
  const float* b_dt   = (const float*)d_in[8];
  const float* W_out  = (const float*)d_in[9];
  float* out = (float*)d_out;

  // workspace (total ~57.9 MB; 57.5 proven, 168 failed):
  //   xz_bf : 32 MB; u_bf : 16 MB; xdbl : 1.5 MB
  //   aprod : B*SEGS*DSTATE*DINNER bf16 = 4.2 MB; hse : 4.2 MB
  // aliases: xb=u_bf; WinT=aprod (8 MB over aprod+hse, dead after gemm1);
  //          WxT=aprod (384 KB, dead before scan1); WoutT=u_bf (after scan3)
  bf16* xz_bf = (bf16*)d_ws;
  bf16* u_bf  = xz_bf + (size_t)ROWS * 4096;
  float* xdbl = (float*)(u_bf + (size_t)ROWS * DINNER);
  bf16* aprod = (bf16*)(xdbl + (size_t)ROWS * 96);
  bf16* hse   = aprod + (size_t)B_SZ * SEGS * DSTATE * DINNER;
  bf16* xb    = u_bf;
  bf16* WinT  = aprod;
  bf16* WxT   = aprod;
  bf16* WoutT = u_bf;

  // 0a) xb = bf16(x)
  cvt_f2b_k<<<(ROWS * DMODEL) / (256 * 8), 256, 0, stream>>>(x, xb);
  // 0b) WinT[4096][1024] = bf16(W_in^T)
  transpose_f2b_k<<<dim3((2 * DINNER) / 32, DMODEL / 32), dim3(32, 8), 0, stream>>>(
      W_in, WinT, DMODEL, 2 * DINNER);
  // 1) xz = x @ W_in  (bf16 MFMA)
  gemm_mfma<bf16><<<dim3((2 * DINNER) / 128, ROWS / 128), 256, 0, stream>>>(
      xb, DMODEL, WinT, DMODEL, xz_bf, 2 * DINNER, DMODEL);
  // 2) u = silu(conv(xz[:, :DINNER]) + conv_b)   (clobbers xb)
  conv_silu_k<<<(ROWS * DINNER) / 256, 256, 0, stream>>>(xz_bf, conv_w, conv_b, u_bf);
  // 3) xdbl = u @ W_x  (split-K MFMA, atomic fp32 combine)
  zero_k<<<(ROWS * 96) / (256 * 4), 256, 0, stream>>>(xdbl);
  transpose_f2b_k<<<dim3(96 / 32, DINNER / 32), dim3(32, 8), 0, stream>>>(
      W_x, WxT, DINNER, 96);
  xdbl_mfma_k<<<dim3(XD_SPLITK, ROWS / 64), 256, 0, stream>>>(u_bf, WxT, xdbl);
  // 4) dt = softplus(xdbl[:, :64] @ W_dt + b_dt) -> xz cols 0..2047
  gemm128<float, bf16, 1><<<dim3(DINNER / TILE, ROWS / TILE), 256, 0, stream>>>(
      xdbl, 96, W_dt, DINNER, xz_bf, 2 * DINNER, DTRANK, b_dt);
  // 5) segmented scan (thread-per-channel); gated -> xz cols 2048..4095
  scan1_k<<<dim3(DINNER / 256, B_SZ * SEGS), 256, 0, stream>>>(
      xz_bf, u_bf, xdbl, A_log, aprod, hse);
  scan2_k<<<dim3(DINNER / 256, B_SZ * DSTATE), 256, 0, stream>>>(aprod, hse);
  scan3_k<<<dim3(DINNER / 256, B_SZ * SEGS), 256, 0, stream>>>(
      xz_bf, u_bf, xdbl, A_log, Dp, hse);
  // 5b) WoutT[1024][2048] = bf16(W_out^T)  (u_bf dead after scan3)
  transpose_f2b_k<<<dim3(DMODEL / 32, DINNER / 32), dim3(32, 8), 0, stream>>>(
      W_out, WoutT, DINNER, DMODEL);
  // 6) out = gated @ W_out  (bf16 MFMA; A = xz cols 2048..4095, lda 4096)
  gemm_mfma<float><<<dim3(DMODEL / 128, ROWS / 128), 256, 0, stream>>>(
      xz_bf + DINNER, 2 * DINNER, WoutT, DINNER, out, DMODEL, DINNER);
}